// Round 1
// baseline (2999.151 us; speedup 1.0000x reference)
//
#include <hip/hip_runtime.h>
#include <math.h>

#define LN_EPS 1e-5f

// ---------------------------------------------------------------------------
// Block-wide sum reduction of two values (256 threads = 4 waves).
// red must be >= 8 floats of LDS scratch.
// ---------------------------------------------------------------------------
__device__ __forceinline__ void block_reduce2(float& s1, float& s2, float* red)
{
    #pragma unroll
    for (int off = 32; off > 0; off >>= 1) {
        s1 += __shfl_down(s1, off);
        s2 += __shfl_down(s2, off);
    }
    const int lane = threadIdx.x & 63;
    const int wid  = threadIdx.x >> 6;
    if (lane == 0) { red[wid * 2] = s1; red[wid * 2 + 1] = s2; }
    __syncthreads();
    s1 = red[0] + red[2] + red[4] + red[6];
    s2 = red[1] + red[3] + red[5] + red[7];
    __syncthreads();   // protect scratch for next use
}

// ---------------------------------------------------------------------------
// Per-node projection (36x32) + joint LayerNorm over [256,36] with affine.
// h[32] in registers; result r[36] in registers (all loops fully unrolled).
// ---------------------------------------------------------------------------
__device__ __forceinline__ void proj_ln(const float* h,
                                        const float* __restrict__ W,
                                        const float* __restrict__ bias,
                                        const float* __restrict__ gamma,
                                        const float* __restrict__ beta,
                                        int n, float* red, float* r)
{
    #pragma unroll
    for (int j = 0; j < 36; ++j) {
        float s = bias[j];
        #pragma unroll
        for (int e = 0; e < 32; ++e) s += h[e] * W[j * 32 + e];
        r[j] = s;
    }
    float s1 = 0.f, s2 = 0.f;
    #pragma unroll
    for (int j = 0; j < 36; ++j) { s1 += r[j]; s2 += r[j] * r[j]; }
    block_reduce2(s1, s2, red);
    const float mu  = s1 * (1.0f / 9216.0f);
    const float var = s2 * (1.0f / 9216.0f) - mu * mu;
    const float rs  = rsqrtf(var + LN_EPS);
    #pragma unroll
    for (int j = 0; j < 36; ++j)
        r[j] = (r[j] - mu) * rs * gamma[n * 36 + j] + beta[n * 36 + j];
}

// ---------------------------------------------------------------------------
// Fused conv stack: one block per batch image, whole pipeline in LDS.
// R1 (40000B) holds h1[16][25][25] then h3[24][19][19]
// R2 (38720B) holds x[28][28]      then h2[20][22][22]
// LDS total 76.9 KB -> 2 blocks/CU.
// ---------------------------------------------------------------------------
__global__ __launch_bounds__(256, 2) void conv_fused_kernel(
    const float* __restrict__ x,
    const float* __restrict__ w1, const float* __restrict__ b1,
    const float* __restrict__ w2, const float* __restrict__ b2,
    const float* __restrict__ w3, const float* __restrict__ b3,
    const float* __restrict__ w4, const float* __restrict__ b4,
    float* __restrict__ hout)
{
    __shared__ __align__(16) float R1[10000];
    __shared__ __align__(16) float R2[9680];

    const int b   = blockIdx.x;
    const int tid = threadIdx.x;

    for (int i = tid; i < 784; i += 256) R2[i] = x[b * 784 + i];
    __syncthreads();

    // ---- conv1: 1 -> 16, 28x28 -> 25x25 (625 pos, up to 3/thread) ----
    {
        const int p0 = tid, p1 = tid + 256;
        const bool v2 = (tid + 512) < 625;
        const int p2 = v2 ? tid + 512 : 624;
        const int y0 = p0 / 25, x0 = p0 % 25;
        const int y1 = p1 / 25, x1 = p1 % 25;
        const int y2 = p2 / 25, x2 = p2 % 25;
        float a0[16], a1[16], a2[16];
        #pragma unroll
        for (int oc = 0; oc < 16; ++oc) { float bb = b1[oc]; a0[oc] = bb; a1[oc] = bb; a2[oc] = bb; }
        #pragma unroll
        for (int k = 0; k < 16; ++k) {
            const int ky = k >> 2, kx = k & 3;
            const float i0 = R2[(y0 + ky) * 28 + x0 + kx];
            const float i1 = R2[(y1 + ky) * 28 + x1 + kx];
            const float i2 = R2[(y2 + ky) * 28 + x2 + kx];
            #pragma unroll
            for (int oc = 0; oc < 16; ++oc) {
                const float w = w1[oc * 16 + k];
                a0[oc] += i0 * w; a1[oc] += i1 * w; a2[oc] += i2 * w;
            }
        }
        #pragma unroll
        for (int oc = 0; oc < 16; ++oc) {
            R1[oc * 625 + p0] = fmaxf(a0[oc], 0.f);
            R1[oc * 625 + p1] = fmaxf(a1[oc], 0.f);
        }
        if (v2) {
            #pragma unroll
            for (int oc = 0; oc < 16; ++oc) R1[oc * 625 + p2] = fmaxf(a2[oc], 0.f);
        }
    }
    __syncthreads();

    // ---- conv2: 16 -> 20, 25x25 -> 22x22 (484 pos, up to 2/thread) ----
    {
        const int p0 = tid;
        const bool v1 = (tid + 256) < 484;
        const int p1 = v1 ? tid + 256 : 483;
        const int y0 = p0 / 22, x0 = p0 % 22;
        const int y1 = p1 / 22, x1 = p1 % 22;
        float a0[20], a1[20];
        #pragma unroll
        for (int oc = 0; oc < 20; ++oc) { float bb = b2[oc]; a0[oc] = bb; a1[oc] = bb; }
        #pragma unroll 1
        for (int ic = 0; ic < 16; ++ic) {
            const float* __restrict__ in = &R1[ic * 625];
            const float* __restrict__ wp = &w2[ic * 16];
            #pragma unroll
            for (int k = 0; k < 16; ++k) {
                const int ky = k >> 2, kx = k & 3;
                const float i0 = in[(y0 + ky) * 25 + x0 + kx];
                const float i1 = in[(y1 + ky) * 25 + x1 + kx];
                #pragma unroll
                for (int oc = 0; oc < 20; ++oc) {
                    const float w = wp[oc * 256 + k];   // w2[(oc*16+ic)*16+k]
                    a0[oc] += i0 * w; a1[oc] += i1 * w;
                }
            }
        }
        __syncthreads();   // all conv2 reads of R1 done before... (R2 writes are safe already; this also fences the next phase ordering)
        #pragma unroll
        for (int oc = 0; oc < 20; ++oc) R2[oc * 484 + p0] = fmaxf(a0[oc], 0.f);
        if (v1) {
            #pragma unroll
            for (int oc = 0; oc < 20; ++oc) R2[oc * 484 + p1] = fmaxf(a1[oc], 0.f);
        }
    }
    __syncthreads();

    // ---- conv3: 20 -> 24, 22x22 -> 19x19 (361 pos, up to 2/thread) ----
    {
        const int p0 = tid;
        const bool v1 = (tid + 256) < 361;
        const int p1 = v1 ? tid + 256 : 360;
        const int y0 = p0 / 19, x0 = p0 % 19;
        const int y1 = p1 / 19, x1 = p1 % 19;
        float a0[24], a1[24];
        #pragma unroll
        for (int oc = 0; oc < 24; ++oc) { float bb = b3[oc]; a0[oc] = bb; a1[oc] = bb; }
        #pragma unroll 1
        for (int ic = 0; ic < 20; ++ic) {
            const float* __restrict__ in = &R2[ic * 484];
            const float* __restrict__ wp = &w3[ic * 16];
            #pragma unroll
            for (int k = 0; k < 16; ++k) {
                const int ky = k >> 2, kx = k & 3;
                const float i0 = in[(y0 + ky) * 22 + x0 + kx];
                const float i1 = in[(y1 + ky) * 22 + x1 + kx];
                #pragma unroll
                for (int oc = 0; oc < 24; ++oc) {
                    const float w = wp[oc * 320 + k];   // w3[(oc*20+ic)*16+k]
                    a0[oc] += i0 * w; a1[oc] += i1 * w;
                }
            }
        }
        __syncthreads();   // conv3 reads of R2 complete before conv4 era / R1 rewrite visibility
        #pragma unroll
        for (int oc = 0; oc < 24; ++oc) R1[oc * 361 + p0] = fmaxf(a0[oc], 0.f);
        if (v1) {
            #pragma unroll
            for (int oc = 0; oc < 24; ++oc) R1[oc * 361 + p1] = fmaxf(a1[oc], 0.f);
        }
    }
    __syncthreads();

    // ---- conv4: 24 -> 30, 19x19 -> 16x16 (256 pos, 1/thread) + coords ----
    {
        const int p  = tid;
        const int oy = p >> 4, ox = p & 15;
        float a[30];
        #pragma unroll
        for (int oc = 0; oc < 30; ++oc) a[oc] = b4[oc];
        #pragma unroll 1
        for (int ic = 0; ic < 24; ++ic) {
            const float* __restrict__ in = &R1[ic * 361];
            const float* __restrict__ wp = &w4[ic * 16];
            #pragma unroll
            for (int k = 0; k < 16; ++k) {
                const int ky = k >> 2, kx = k & 3;
                const float iv = in[(oy + ky) * 19 + ox + kx];
                #pragma unroll
                for (int oc = 0; oc < 30; ++oc)
                    a[oc] += iv * wp[oc * 384 + k];    // w4[(oc*24+ic)*16+k]
            }
        }
        float* __restrict__ o = hout + ((size_t)b * 256 + p) * 32;
        #pragma unroll
        for (int oc = 0; oc < 30; ++oc) o[oc] = fmaxf(a[oc], 0.f);
        o[30] = (float)ox * (1.0f / 16.0f);   // xcoord = x/cw
        o[31] = (float)oy * (1.0f / 16.0f);   // ycoord = y/ch
    }
}

// ---------------------------------------------------------------------------
// Fused attention + head: one block per batch element, thread = node.
// sK/sV row-major [256][36] (144B rows, 16B aligned -> b128 broadcast reads).
// LDS 72 KB -> 2 blocks/CU.
// ---------------------------------------------------------------------------
__global__ __launch_bounds__(256, 2) void attn_head_kernel(
    const float* __restrict__ hbuf,
    const float* __restrict__ kW, const float* __restrict__ kb,
    const float* __restrict__ qW, const float* __restrict__ qb,
    const float* __restrict__ vW, const float* __restrict__ vb,
    const float* __restrict__ kg, const float* __restrict__ kbeta,
    const float* __restrict__ qg, const float* __restrict__ qbeta,
    const float* __restrict__ vg, const float* __restrict__ vbeta,
    const float* __restrict__ l1W, const float* __restrict__ l1b,
    const float* __restrict__ l2W, const float* __restrict__ l2b,
    float* __restrict__ out)
{
    __shared__ __align__(16) float sK[256 * 36];
    __shared__ __align__(16) float sV[256 * 36];
    __shared__ float red[8];

    const int b = blockIdx.x;
    const int n = threadIdx.x;

    float h[32];
    {
        const float4* hp = (const float4*)(hbuf + ((size_t)b * 256 + n) * 32);
        #pragma unroll
        for (int e4 = 0; e4 < 8; ++e4) {
            const float4 t = hp[e4];
            h[e4 * 4 + 0] = t.x; h[e4 * 4 + 1] = t.y;
            h[e4 * 4 + 2] = t.z; h[e4 * 4 + 3] = t.w;
        }
    }

    // K projection + LN -> sK
    {
        float r[36];
        proj_ln(h, kW, kb, kg, kbeta, n, red, r);
        #pragma unroll
        for (int j4 = 0; j4 < 9; ++j4) {
            float4 t;
            t.x = r[j4 * 4 + 0]; t.y = r[j4 * 4 + 1];
            t.z = r[j4 * 4 + 2]; t.w = r[j4 * 4 + 3];
            *((float4*)&sK[n * 36 + j4 * 4]) = t;
        }
    }
    // V projection + LN -> sV
    {
        float r[36];
        proj_ln(h, vW, vb, vg, vbeta, n, red, r);
        #pragma unroll
        for (int j4 = 0; j4 < 9; ++j4) {
            float4 t;
            t.x = r[j4 * 4 + 0]; t.y = r[j4 * 4 + 1];
            t.z = r[j4 * 4 + 2]; t.w = r[j4 * 4 + 3];
            *((float4*)&sV[n * 36 + j4 * 4]) = t;
        }
    }
    // Q projection + LN -> registers
    float q[36];
    proj_ln(h, qW, qb, qg, qbeta, n, red, q);
    __syncthreads();   // sK/sV fully visible

    // ---- online-softmax attention over 256 keys ----
    float m = -1e30f, l = 0.f;
    float acc[36];
    #pragma unroll
    for (int j = 0; j < 36; ++j) acc[j] = 0.f;

    for (int g = 0; g < 256; ++g) {
        const float4* kr = (const float4*)&sK[g * 36];
        float s = 0.f;
        #pragma unroll
        for (int j4 = 0; j4 < 9; ++j4) {
            const float4 kk = kr[j4];
            s += q[j4 * 4 + 0] * kk.x + q[j4 * 4 + 1] * kk.y
               + q[j4 * 4 + 2] * kk.z + q[j4 * 4 + 3] * kk.w;
        }
        s *= (1.0f / 6.0f);                       // / sqrt(36)
        if (s > m) {                              // exec-masked rescale (rare)
            const float c = __expf(m - s);
            l *= c;
            #pragma unroll
            for (int j = 0; j < 36; ++j) acc[j] *= c;
            m = s;
        }
        const float p = __expf(s - m);
        l += p;
        const float4* vr = (const float4*)&sV[g * 36];
        #pragma unroll
        for (int j4 = 0; j4 < 9; ++j4) {
            const float4 vv = vr[j4];
            acc[j4 * 4 + 0] += p * vv.x; acc[j4 * 4 + 1] += p * vv.y;
            acc[j4 * 4 + 2] += p * vv.z; acc[j4 * 4 + 3] += p * vv.w;
        }
    }
    const float invl = 1.0f / l;
    float att[36];
    #pragma unroll
    for (int j = 0; j < 36; ++j) att[j] = acc[j] * invl;

    // ---- l1 + ReLU ----
    float a2[36];
    #pragma unroll
    for (int jj = 0; jj < 36; ++jj) {
        float s = l1b[jj];
        #pragma unroll
        for (int d = 0; d < 36; ++d) s += att[d] * l1W[jj * 36 + d];
        a2[jj] = fmaxf(s, 0.f);
    }

    // ---- joint LN (no affine) ----
    float s1 = 0.f, s2 = 0.f;
    #pragma unroll
    for (int j = 0; j < 36; ++j) { s1 += a2[j]; s2 += a2[j] * a2[j]; }
    block_reduce2(s1, s2, red);   // its syncs also fence all attention-phase sK/sV reads
    const float mu  = s1 * (1.0f / 9216.0f);
    const float var = s2 * (1.0f / 9216.0f) - mu * mu;
    const float rs  = rsqrtf(var + LN_EPS);

    // write normalized rows into sK for the node-max reduction
    #pragma unroll
    for (int j4 = 0; j4 < 9; ++j4) {
        float4 t;
        t.x = (a2[j4 * 4 + 0] - mu) * rs; t.y = (a2[j4 * 4 + 1] - mu) * rs;
        t.z = (a2[j4 * 4 + 2] - mu) * rs; t.w = (a2[j4 * 4 + 3] - mu) * rs;
        *((float4*)&sK[n * 36 + j4 * 4]) = t;
    }
    __syncthreads();

    // tree max over the 256 nodes, per feature
    #pragma unroll 1
    for (int stride = 128; stride >= 1; stride >>= 1) {
        if (n < stride) {
            #pragma unroll
            for (int j = 0; j < 36; ++j)
                sK[n * 36 + j] = fmaxf(sK[n * 36 + j], sK[(n + stride) * 36 + j]);
        }
        __syncthreads();
    }

    // ---- head: 36 -> 10, log_softmax ----
    if (n == 0) {
        float y[10];
        #pragma unroll
        for (int c = 0; c < 10; ++c) {
            float s = l2b[c];
            #pragma unroll
            for (int j = 0; j < 36; ++j) s += sK[j] * l2W[c * 36 + j];
            y[c] = s;
        }
        float mx = y[0];
        #pragma unroll
        for (int c = 1; c < 10; ++c) mx = fmaxf(mx, y[c]);
        float se = 0.f;
        #pragma unroll
        for (int c = 0; c < 10; ++c) se += __expf(y[c] - mx);
        const float lse = mx + logf(se);
        #pragma unroll
        for (int c = 0; c < 10; ++c) out[b * 10 + c] = y[c] - lse;
    }
}

// ---------------------------------------------------------------------------
extern "C" void kernel_launch(void* const* d_in, const int* in_sizes, int n_in,
                              void* d_out, int out_size, void* d_ws, size_t ws_size,
                              hipStream_t stream)
{
    const float* x     = (const float*)d_in[0];
    const float* w1    = (const float*)d_in[1];
    const float* b1    = (const float*)d_in[2];
    const float* w2    = (const float*)d_in[3];
    const float* b2    = (const float*)d_in[4];
    const float* w3    = (const float*)d_in[5];
    const float* b3    = (const float*)d_in[6];
    const float* w4    = (const float*)d_in[7];
    const float* b4    = (const float*)d_in[8];
    const float* kW    = (const float*)d_in[9];
    const float* kb    = (const float*)d_in[10];
    const float* qW    = (const float*)d_in[11];
    const float* qb    = (const float*)d_in[12];
    const float* vW    = (const float*)d_in[13];
    const float* vb    = (const float*)d_in[14];
    const float* kg    = (const float*)d_in[15];
    const float* kbeta = (const float*)d_in[16];
    const float* qg    = (const float*)d_in[17];
    const float* qbeta = (const float*)d_in[18];
    const float* vg    = (const float*)d_in[19];
    const float* vbeta = (const float*)d_in[20];
    const float* l1W   = (const float*)d_in[21];
    const float* l1b   = (const float*)d_in[22];
    const float* l2W   = (const float*)d_in[23];
    const float* l2b   = (const float*)d_in[24];

    const int B = in_sizes[0] / (28 * 28);     // 2048
    float* hbuf = (float*)d_ws;                // [B,256,32] = 64 MiB

    conv_fused_kernel<<<dim3(B), dim3(256), 0, stream>>>(
        x, w1, b1, w2, b2, w3, b3, w4, b4, hbuf);
    attn_head_kernel<<<dim3(B), dim3(256), 0, stream>>>(
        hbuf, kW, kb, qW, qb, vW, vb,
        kg, kbeta, qg, qbeta, vg, vbeta,
        l1W, l1b, l2W, l2b, (float*)d_out);
}

// Round 2
// 813.389 us; speedup vs baseline: 3.6872x; 3.6872x over previous
//
#include <hip/hip_runtime.h>
#include <math.h>

#define LN_EPS 1e-5f

typedef _Float16 half_t;
typedef _Float16 half8_t __attribute__((ext_vector_type(8)));
typedef _Float16 half2_t __attribute__((ext_vector_type(2)));
typedef float f32x4 __attribute__((ext_vector_type(4)));

// ===========================================================================
// Weight-prep: reorder conv weights into MFMA B-fragment order (fp16).
// Frag element (layer, sn=s*2+nt, lane l, j): oc = nt*16 + (l&15),
// k = s*32 + (l>>4)*8 + j, with k = ky*(4*Cp) + kx*Cp + ic  (HWC im2col order).
// F2: 16 rows, F3/F4: 24 rows; row = 64 lanes x 8 half = 1 KB.
// ===========================================================================
__global__ void prep_weights_kernel(const float* __restrict__ w2,
                                    const float* __restrict__ w3,
                                    const float* __restrict__ w4,
                                    half_t* __restrict__ F2,
                                    half_t* __restrict__ F3,
                                    half_t* __restrict__ F4)
{
    const int bid = blockIdx.x;
    const int t   = threadIdx.x;
    const int flat0 = t * 2;              // two consecutive j's per thread
    const int l  = flat0 >> 3;
    const int j0 = flat0 & 7;

    int layer, sn;
    half_t* dst;
    if (bid < 16)      { layer = 2; sn = bid;      dst = F2; }
    else if (bid < 40) { layer = 3; sn = bid - 16; dst = F3; }
    else               { layer = 4; sn = bid - 40; dst = F4; }
    const int s  = sn >> 1;
    const int nt = sn & 1;
    const int oc = nt * 16 + (l & 15);

    float v[2];
    #pragma unroll
    for (int u = 0; u < 2; ++u) {
        const int j = j0 + u;
        const int k = s * 32 + ((l >> 4) * 8) + j;
        float val = 0.f;
        if (layer == 2) {
            const int ky = k >> 6, rem = k & 63, kx = rem >> 4, ic = rem & 15;
            if (oc < 20) val = w2[(oc * 16 + ic) * 16 + ky * 4 + kx];
        } else if (layer == 3) {
            const int ky = k / 96, rem = k % 96, kx = rem / 24, ic = rem % 24;
            if (oc < 24 && ic < 20) val = w3[(oc * 20 + ic) * 16 + ky * 4 + kx];
        } else {
            const int ky = k / 96, rem = k % 96, kx = rem / 24, ic = rem % 24;
            if (oc < 30) val = w4[(oc * 24 + ic) * 16 + ky * 4 + kx];
        }
        v[u] = val;
    }
    half2_t out;
    out[0] = (half_t)v[0];
    out[1] = (half_t)v[1];
    *(half2_t*)&dst[(sn * 64 + l) * 8 + j0] = out;
}

// ===========================================================================
// Fused conv stack, MFMA implicit GEMM. One block per image, 256 thr (4 waves).
// LDS layout (bytes):
//   [0, 23232)      plane2 (22x22x24 HWC fp16); overlaid at start: x(784f)+w1(256f)+b1(16f)
//   [23232, 43232)  plane1 (25x25x16 HWC fp16); later plane3 (19x19x24, 17328B)
//   [43232, 45280)  slack for M-padding overflow reads
// ===========================================================================
__global__ __launch_bounds__(256, 2) void conv_fused_kernel(
    const float* __restrict__ x,
    const float* __restrict__ w1, const float* __restrict__ b1,
    const float* __restrict__ b2, const float* __restrict__ b3,
    const float* __restrict__ b4,
    const half_t* __restrict__ F2, const half_t* __restrict__ F3,
    const half_t* __restrict__ F4,
    half_t* __restrict__ hout)
{
    __shared__ __attribute__((aligned(16))) char LBUF[45280];
    float*  xw = (float*)LBUF;                       // x[784], w1T[256], b1[16]
    char*   plane2b = LBUF;                          // after conv1, xw is dead
    char*   plane1b = LBUF + 23232;
    half_t* plane2h = (half_t*)plane2b;
    half_t* plane1h = (half_t*)plane1b;
    half_t* plane3h = (half_t*)plane1b;              // overlay (conv2 out dead)

    const int b    = blockIdx.x;
    const int tid  = threadIdx.x;
    const int wave = tid >> 6;
    const int l    = tid & 63;
    const int col  = l & 15;     // MFMA free-index lane mapping
    const int g    = l >> 4;     // k-group

    // ---- stage x, w1 (transposed to [k][oc]), b1 into LDS ----
    {
        const float4* gx = (const float4*)(x + (size_t)b * 784);
        if (tid < 196) ((float4*)xw)[tid] = gx[tid];
        // w1 src [oc][k] -> dst [k][oc]
        const int i = tid;
        if (i < 256) xw[784 + (i & 15) * 16 + (i >> 4)] = w1[i];
        if (tid < 16) xw[1040 + tid] = b1[tid];
    }
    // B-fragments for conv2 (issued early; vmcnt-covered by compiler)
    half8_t B2f[8][2];
    {
        const half8_t* Fv = (const half8_t*)F2;
        #pragma unroll
        for (int s = 0; s < 8; ++s) {
            B2f[s][0] = Fv[(s * 2 + 0) * 64 + l];
            B2f[s][1] = Fv[(s * 2 + 1) * 64 + l];
        }
    }
    __syncthreads();

    // ---- conv1 (fp32 VALU): 1->16, 28x28 -> 25x25, HWC fp16 out ----
    {
        const float* xs  = xw;
        const float* w1s = xw + 784;    // [k][oc]
        const float* b1s = xw + 1040;
        const int p0 = tid, p1 = tid + 256;
        const bool v2 = (tid + 512) < 625;
        const int p2 = v2 ? tid + 512 : 624;
        const int y0 = p0 / 25, x0 = p0 % 25;
        const int y1 = p1 / 25, x1 = p1 % 25;
        const int y2 = p2 / 25, x2 = p2 % 25;
        float a0[16], a1[16], a2[16];
        #pragma unroll
        for (int oc = 0; oc < 16; ++oc) { const float bb = b1s[oc]; a0[oc] = bb; a1[oc] = bb; a2[oc] = bb; }
        #pragma unroll
        for (int k = 0; k < 16; ++k) {
            const int ky = k >> 2, kx = k & 3;
            const float i0 = xs[(y0 + ky) * 28 + x0 + kx];
            const float i1 = xs[(y1 + ky) * 28 + x1 + kx];
            const float i2 = xs[(y2 + ky) * 28 + x2 + kx];
            #pragma unroll
            for (int oc4 = 0; oc4 < 4; ++oc4) {
                const float4 wv = *(const float4*)&w1s[k * 16 + oc4 * 4];
                const float wq[4] = {wv.x, wv.y, wv.z, wv.w};
                #pragma unroll
                for (int q = 0; q < 4; ++q) {
                    const int oc = oc4 * 4 + q;
                    a0[oc] += i0 * wq[q]; a1[oc] += i1 * wq[q]; a2[oc] += i2 * wq[q];
                }
            }
        }
        #pragma unroll
        for (int i2_ = 0; i2_ < 8; ++i2_) {
            half2_t h0, h1;
            h0[0] = (half_t)fmaxf(a0[2 * i2_], 0.f); h0[1] = (half_t)fmaxf(a0[2 * i2_ + 1], 0.f);
            h1[0] = (half_t)fmaxf(a1[2 * i2_], 0.f); h1[1] = (half_t)fmaxf(a1[2 * i2_ + 1], 0.f);
            *(half2_t*)&plane1h[p0 * 16 + 2 * i2_] = h0;
            *(half2_t*)&plane1h[p1 * 16 + 2 * i2_] = h1;
        }
        if (v2) {
            #pragma unroll
            for (int i2_ = 0; i2_ < 8; ++i2_) {
                half2_t h2v;
                h2v[0] = (half_t)fmaxf(a2[2 * i2_], 0.f); h2v[1] = (half_t)fmaxf(a2[2 * i2_ + 1], 0.f);
                *(half2_t*)&plane1h[p2 * 16 + 2 * i2_] = h2v;
            }
        }
    }
    __syncthreads();

    // ---- conv2 (MFMA): 16->20(pad24), 25x25 -> 22x22, K=256 (8 steps) ----
    {
        const float bias0 = b2[col];
        const float bias1 = (16 + col < 20) ? b2[16 + col] : 0.f;
        #pragma unroll 1
        for (int mt = wave; mt < 31; mt += 4) {
            const int pos = mt * 16 + col;
            const int py = pos / 22, px = pos - py * 22;
            const char* Ab = plane1b + (py * 25 + px) * 32 + g * 16;
            f32x4 c0 = {0.f, 0.f, 0.f, 0.f}, c1 = {0.f, 0.f, 0.f, 0.f};
            #pragma unroll
            for (int s = 0; s < 8; ++s) {
                const half8_t a = *(const half8_t*)(Ab + (s >> 1) * 800 + (s & 1) * 64);
                c0 = __builtin_amdgcn_mfma_f32_16x16x32_f16(a, B2f[s][0], c0, 0, 0, 0);
                c1 = __builtin_amdgcn_mfma_f32_16x16x32_f16(a, B2f[s][1], c1, 0, 0, 0);
            }
            #pragma unroll
            for (int r = 0; r < 4; ++r) {
                const int prow = mt * 16 + g * 4 + r;
                if (prow < 484) {
                    plane2h[prow * 24 + col] = (half_t)fmaxf(c0[r] + bias0, 0.f);
                    if (col < 8) {   // oc1 = 16+col < 24 (20..23 forced to 0)
                        const float v = (col < 4) ? fmaxf(c1[r] + bias1, 0.f) : 0.f;
                        plane2h[prow * 24 + 16 + col] = (half_t)v;
                    }
                }
            }
        }
    }
    // B-fragments for conv3
    half8_t B3f[12][2];
    {
        const half8_t* Fv = (const half8_t*)F3;
        #pragma unroll
        for (int s = 0; s < 12; ++s) {
            B3f[s][0] = Fv[(s * 2 + 0) * 64 + l];
            B3f[s][1] = Fv[(s * 2 + 1) * 64 + l];
        }
    }
    __syncthreads();

    // ---- conv3 (MFMA): 24(in,pad)->24, 22x22 -> 19x19, K=384 (12 steps) ----
    {
        const float bias0 = b3[col];
        const float bias1 = b3[16 + (col & 7)];   // only col<8 lanes use it
        #pragma unroll 1
        for (int mt = wave; mt < 23; mt += 4) {
            const int pos = mt * 16 + col;
            const int py = pos / 19, px = pos - py * 19;
            const char* Ab = plane2b + (py * 22 + px) * 48 + g * 16;
            f32x4 c0 = {0.f, 0.f, 0.f, 0.f}, c1 = {0.f, 0.f, 0.f, 0.f};
            #pragma unroll
            for (int s = 0; s < 12; ++s) {
                const half8_t a = *(const half8_t*)(Ab + (s / 3) * 1056 + (s % 3) * 64);
                c0 = __builtin_amdgcn_mfma_f32_16x16x32_f16(a, B3f[s][0], c0, 0, 0, 0);
                c1 = __builtin_amdgcn_mfma_f32_16x16x32_f16(a, B3f[s][1], c1, 0, 0, 0);
            }
            #pragma unroll
            for (int r = 0; r < 4; ++r) {
                const int prow = mt * 16 + g * 4 + r;
                if (prow < 361) {
                    plane3h[prow * 24 + col] = (half_t)fmaxf(c0[r] + bias0, 0.f);
                    if (col < 8)
                        plane3h[prow * 24 + 16 + col] = (half_t)fmaxf(c1[r] + bias1, 0.f);
                }
            }
        }
    }
    // B-fragments for conv4
    half8_t B4f[12][2];
    {
        const half8_t* Fv = (const half8_t*)F4;
        #pragma unroll
        for (int s = 0; s < 12; ++s) {
            B4f[s][0] = Fv[(s * 2 + 0) * 64 + l];
            B4f[s][1] = Fv[(s * 2 + 1) * 64 + l];
        }
    }
    __syncthreads();

    // ---- conv4 (MFMA): 24->30, 19x19 -> 16x16, K=384; out -> global fp16 ----
    {
        const float bias0 = b4[col];
        const float bias1 = (16 + col < 30) ? b4[16 + col] : 0.f;
        half_t* hb = hout + (size_t)b * 256 * 32;
        #pragma unroll 1
        for (int mt = wave; mt < 16; mt += 4) {
            const int pos = mt * 16 + col;
            const int py = pos >> 4, px = pos & 15;
            const char* Ab = plane1b + (py * 19 + px) * 48 + g * 16;   // plane3
            f32x4 c0 = {0.f, 0.f, 0.f, 0.f}, c1 = {0.f, 0.f, 0.f, 0.f};
            #pragma unroll
            for (int s = 0; s < 12; ++s) {
                const half8_t a = *(const half8_t*)(Ab + (s / 3) * 912 + (s % 3) * 64);
                c0 = __builtin_amdgcn_mfma_f32_16x16x32_f16(a, B4f[s][0], c0, 0, 0, 0);
                c1 = __builtin_amdgcn_mfma_f32_16x16x32_f16(a, B4f[s][1], c1, 0, 0, 0);
            }
            #pragma unroll
            for (int r = 0; r < 4; ++r) {
                const int prow = mt * 16 + g * 4 + r;   // < 256 always
                hb[prow * 32 + col] = (half_t)fmaxf(c0[r] + bias0, 0.f);
                if (col < 14)
                    hb[prow * 32 + 16 + col] = (half_t)fmaxf(c1[r] + bias1, 0.f);
            }
        }
        // coord channels
        hb[tid * 32 + 30] = (half_t)((float)(tid & 15) * 0.0625f);
        hb[tid * 32 + 31] = (half_t)((float)(tid >> 4) * 0.0625f);
    }
}

// ===========================================================================
// Attention + head (unchanged math, fp16 h input).
// ===========================================================================
__device__ __forceinline__ void block_reduce2(float& s1, float& s2, float* red)
{
    #pragma unroll
    for (int off = 32; off > 0; off >>= 1) {
        s1 += __shfl_down(s1, off);
        s2 += __shfl_down(s2, off);
    }
    const int lane = threadIdx.x & 63;
    const int wid  = threadIdx.x >> 6;
    if (lane == 0) { red[wid * 2] = s1; red[wid * 2 + 1] = s2; }
    __syncthreads();
    s1 = red[0] + red[2] + red[4] + red[6];
    s2 = red[1] + red[3] + red[5] + red[7];
    __syncthreads();
}

__device__ __forceinline__ void proj_ln(const float* h,
                                        const float* __restrict__ W,
                                        const float* __restrict__ bias,
                                        const float* __restrict__ gamma,
                                        const float* __restrict__ beta,
                                        int n, float* red, float* r)
{
    #pragma unroll
    for (int j = 0; j < 36; ++j) {
        float s = bias[j];
        #pragma unroll
        for (int e = 0; e < 32; ++e) s += h[e] * W[j * 32 + e];
        r[j] = s;
    }
    float s1 = 0.f, s2 = 0.f;
    #pragma unroll
    for (int j = 0; j < 36; ++j) { s1 += r[j]; s2 += r[j] * r[j]; }
    block_reduce2(s1, s2, red);
    const float mu  = s1 * (1.0f / 9216.0f);
    const float var = s2 * (1.0f / 9216.0f) - mu * mu;
    const float rs  = rsqrtf(var + LN_EPS);
    #pragma unroll
    for (int j = 0; j < 36; ++j)
        r[j] = (r[j] - mu) * rs * gamma[n * 36 + j] + beta[n * 36 + j];
}

__global__ __launch_bounds__(256, 2) void attn_head_kernel(
    const half_t* __restrict__ hbuf,
    const float* __restrict__ kW, const float* __restrict__ kb,
    const float* __restrict__ qW, const float* __restrict__ qb,
    const float* __restrict__ vW, const float* __restrict__ vb,
    const float* __restrict__ kg, const float* __restrict__ kbeta,
    const float* __restrict__ qg, const float* __restrict__ qbeta,
    const float* __restrict__ vg, const float* __restrict__ vbeta,
    const float* __restrict__ l1W, const float* __restrict__ l1b,
    const float* __restrict__ l2W, const float* __restrict__ l2b,
    float* __restrict__ out)
{
    __shared__ __attribute__((aligned(16))) float sK[256 * 36];
    __shared__ __attribute__((aligned(16))) float sV[256 * 36];
    __shared__ float red[8];

    const int b = blockIdx.x;
    const int n = threadIdx.x;

    float h[32];
    {
        const half8_t* hp = (const half8_t*)(hbuf + ((size_t)b * 256 + n) * 32);
        #pragma unroll
        for (int i = 0; i < 4; ++i) {
            const half8_t hv = hp[i];
            #pragma unroll
            for (int j = 0; j < 8; ++j) h[i * 8 + j] = (float)hv[j];
        }
    }

    {
        float r[36];
        proj_ln(h, kW, kb, kg, kbeta, n, red, r);
        #pragma unroll
        for (int j4 = 0; j4 < 9; ++j4) {
            float4 t;
            t.x = r[j4 * 4 + 0]; t.y = r[j4 * 4 + 1];
            t.z = r[j4 * 4 + 2]; t.w = r[j4 * 4 + 3];
            *((float4*)&sK[n * 36 + j4 * 4]) = t;
        }
    }
    {
        float r[36];
        proj_ln(h, vW, vb, vg, vbeta, n, red, r);
        #pragma unroll
        for (int j4 = 0; j4 < 9; ++j4) {
            float4 t;
            t.x = r[j4 * 4 + 0]; t.y = r[j4 * 4 + 1];
            t.z = r[j4 * 4 + 2]; t.w = r[j4 * 4 + 3];
            *((float4*)&sV[n * 36 + j4 * 4]) = t;
        }
    }
    float q[36];
    proj_ln(h, qW, qb, qg, qbeta, n, red, q);
    __syncthreads();

    float m = -1e30f, lsum = 0.f;
    float acc[36];
    #pragma unroll
    for (int j = 0; j < 36; ++j) acc[j] = 0.f;

    for (int gk = 0; gk < 256; ++gk) {
        const float4* kr = (const float4*)&sK[gk * 36];
        float s = 0.f;
        #pragma unroll
        for (int j4 = 0; j4 < 9; ++j4) {
            const float4 kk = kr[j4];
            s += q[j4 * 4 + 0] * kk.x + q[j4 * 4 + 1] * kk.y
               + q[j4 * 4 + 2] * kk.z + q[j4 * 4 + 3] * kk.w;
        }
        s *= (1.0f / 6.0f);
        if (s > m) {
            const float c = __expf(m - s);
            lsum *= c;
            #pragma unroll
            for (int j = 0; j < 36; ++j) acc[j] *= c;
            m = s;
        }
        const float p = __expf(s - m);
        lsum += p;
        const float4* vr = (const float4*)&sV[gk * 36];
        #pragma unroll
        for (int j4 = 0; j4 < 9; ++j4) {
            const float4 vv = vr[j4];
            acc[j4 * 4 + 0] += p * vv.x; acc[j4 * 4 + 1] += p * vv.y;
            acc[j4 * 4 + 2] += p * vv.z; acc[j4 * 4 + 3] += p * vv.w;
        }
    }
    const float invl = 1.0f / lsum;
    float att[36];
    #pragma unroll
    for (int j = 0; j < 36; ++j) att[j] = acc[j] * invl;

    float a2[36];
    #pragma unroll
    for (int jj = 0; jj < 36; ++jj) {
        float s = l1b[jj];
        #pragma unroll
        for (int d = 0; d < 36; ++d) s += att[d] * l1W[jj * 36 + d];
        a2[jj] = fmaxf(s, 0.f);
    }

    float s1 = 0.f, s2 = 0.f;
    #pragma unroll
    for (int j = 0; j < 36; ++j) { s1 += a2[j]; s2 += a2[j] * a2[j]; }
    block_reduce2(s1, s2, red);
    const float mu  = s1 * (1.0f / 9216.0f);
    const float var = s2 * (1.0f / 9216.0f) - mu * mu;
    const float rs  = rsqrtf(var + LN_EPS);

    #pragma unroll
    for (int j4 = 0; j4 < 9; ++j4) {
        float4 t;
        t.x = (a2[j4 * 4 + 0] - mu) * rs; t.y = (a2[j4 * 4 + 1] - mu) * rs;
        t.z = (a2[j4 * 4 + 2] - mu) * rs; t.w = (a2[j4 * 4 + 3] - mu) * rs;
        *((float4*)&sK[n * 36 + j4 * 4]) = t;
    }
    __syncthreads();

    #pragma unroll 1
    for (int stride = 128; stride >= 1; stride >>= 1) {
        if (n < stride) {
            #pragma unroll
            for (int j = 0; j < 36; ++j)
                sK[n * 36 + j] = fmaxf(sK[n * 36 + j], sK[(n + stride) * 36 + j]);
        }
        __syncthreads();
    }

    if (n == 0) {
        float y[10];
        #pragma unroll
        for (int c = 0; c < 10; ++c) {
            float s = l2b[c];
            #pragma unroll
            for (int j = 0; j < 36; ++j) s += sK[j] * l2W[c * 36 + j];
            y[c] = s;
        }
        float mx = y[0];
        #pragma unroll
        for (int c = 1; c < 10; ++c) mx = fmaxf(mx, y[c]);
        float se = 0.f;
        #pragma unroll
        for (int c = 0; c < 10; ++c) se += __expf(y[c] - mx);
        const float lse = mx + logf(se);
        #pragma unroll
        for (int c = 0; c < 10; ++c) out[b * 10 + c] = y[c] - lse;
    }
}

// ===========================================================================
extern "C" void kernel_launch(void* const* d_in, const int* in_sizes, int n_in,
                              void* d_out, int out_size, void* d_ws, size_t ws_size,
                              hipStream_t stream)
{
    const float* x     = (const float*)d_in[0];
    const float* w1    = (const float*)d_in[1];
    const float* b1    = (const float*)d_in[2];
    const float* w2    = (const float*)d_in[3];
    const float* b2    = (const float*)d_in[4];
    const float* w3    = (const float*)d_in[5];
    const float* b3    = (const float*)d_in[6];
    const float* w4    = (const float*)d_in[7];
    const float* b4    = (const float*)d_in[8];
    const float* kW    = (const float*)d_in[9];
    const float* kb    = (const float*)d_in[10];
    const float* qW    = (const float*)d_in[11];
    const float* qb    = (const float*)d_in[12];
    const float* vW    = (const float*)d_in[13];
    const float* vb    = (const float*)d_in[14];
    const float* kg    = (const float*)d_in[15];
    const float* kbeta = (const float*)d_in[16];
    const float* qg    = (const float*)d_in[17];
    const float* qbeta = (const float*)d_in[18];
    const float* vg    = (const float*)d_in[19];
    const float* vbeta = (const float*)d_in[20];
    const float* l1W   = (const float*)d_in[21];
    const float* l1b   = (const float*)d_in[22];
    const float* l2W   = (const float*)d_in[23];
    const float* l2b   = (const float*)d_in[24];

    const int B = in_sizes[0] / (28 * 28);            // 2048
    half_t* hbuf = (half_t*)d_ws;                     // [B,256,32] fp16 = 33.5 MB
    half_t* F2 = (half_t*)((char*)d_ws + 33554432);   // 16 KB
    half_t* F3 = F2 + 8192;                           // 24 KB
    half_t* F4 = F3 + 12288;                          // 24 KB

    prep_weights_kernel<<<dim3(64), dim3(256), 0, stream>>>(w2, w3, w4, F2, F3, F4);
    conv_fused_kernel<<<dim3(B), dim3(256), 0, stream>>>(
        x, w1, b1, b2, b3, b4, F2, F3, F4, hbuf);
    attn_head_kernel<<<dim3(B), dim3(256), 0, stream>>>(
        hbuf, kW, kb, qW, qb, vW, vb,
        kg, kbeta, qg, qbeta, vg, vbeta,
        l1W, l1b, l2W, l2b, (float*)d_out);
}

// Round 3
// 387.497 us; speedup vs baseline: 7.7398x; 2.0991x over previous
//
#include <hip/hip_runtime.h>
#include <math.h>

#define LN_EPS 1e-5f

typedef _Float16 half_t;
typedef _Float16 half8_t __attribute__((ext_vector_type(8)));
typedef _Float16 half4_t __attribute__((ext_vector_type(4)));
typedef _Float16 half2_t __attribute__((ext_vector_type(2)));
typedef float f32x4 __attribute__((ext_vector_type(4)));

// ===========================================================================
// Weight-prep: reorder conv weights into MFMA B-fragment order (fp16).
// ===========================================================================
__global__ void prep_weights_kernel(const float* __restrict__ w2,
                                    const float* __restrict__ w3,
                                    const float* __restrict__ w4,
                                    half_t* __restrict__ F2,
                                    half_t* __restrict__ F3,
                                    half_t* __restrict__ F4)
{
    const int bid = blockIdx.x;
    const int t   = threadIdx.x;
    const int flat0 = t * 2;
    const int l  = flat0 >> 3;
    const int j0 = flat0 & 7;

    int layer, sn;
    half_t* dst;
    if (bid < 16)      { layer = 2; sn = bid;      dst = F2; }
    else if (bid < 40) { layer = 3; sn = bid - 16; dst = F3; }
    else               { layer = 4; sn = bid - 40; dst = F4; }
    const int s  = sn >> 1;
    const int nt = sn & 1;
    const int oc = nt * 16 + (l & 15);

    float v[2];
    #pragma unroll
    for (int u = 0; u < 2; ++u) {
        const int j = j0 + u;
        const int k = s * 32 + ((l >> 4) * 8) + j;
        float val = 0.f;
        if (layer == 2) {
            const int ky = k >> 6, rem = k & 63, kx = rem >> 4, ic = rem & 15;
            if (oc < 20) val = w2[(oc * 16 + ic) * 16 + ky * 4 + kx];
        } else if (layer == 3) {
            const int ky = k / 96, rem = k % 96, kx = rem / 24, ic = rem % 24;
            if (oc < 24 && ic < 20) val = w3[(oc * 20 + ic) * 16 + ky * 4 + kx];
        } else {
            const int ky = k / 96, rem = k % 96, kx = rem / 24, ic = rem % 24;
            if (oc < 30) val = w4[(oc * 24 + ic) * 16 + ky * 4 + kx];
        }
        v[u] = val;
    }
    half2_t outv;
    outv[0] = (half_t)v[0];
    outv[1] = (half_t)v[1];
    *(half2_t*)&dst[(sn * 64 + l) * 8 + j0] = outv;
}

// ===========================================================================
// Fused conv stack, MFMA implicit GEMM (unchanged from R2 — passing).
// ===========================================================================
__global__ __launch_bounds__(256, 2) void conv_fused_kernel(
    const float* __restrict__ x,
    const float* __restrict__ w1, const float* __restrict__ b1,
    const float* __restrict__ b2, const float* __restrict__ b3,
    const float* __restrict__ b4,
    const half_t* __restrict__ F2, const half_t* __restrict__ F3,
    const half_t* __restrict__ F4,
    half_t* __restrict__ hout)
{
    __shared__ __attribute__((aligned(16))) char LBUF[45280];
    float*  xw = (float*)LBUF;
    char*   plane2b = LBUF;
    char*   plane1b = LBUF + 23232;
    half_t* plane2h = (half_t*)plane2b;
    half_t* plane1h = (half_t*)plane1b;
    half_t* plane3h = (half_t*)plane1b;

    const int b    = blockIdx.x;
    const int tid  = threadIdx.x;
    const int wave = tid >> 6;
    const int l    = tid & 63;
    const int col  = l & 15;
    const int g    = l >> 4;

    {
        const float4* gx = (const float4*)(x + (size_t)b * 784);
        if (tid < 196) ((float4*)xw)[tid] = gx[tid];
        const int i = tid;
        if (i < 256) xw[784 + (i & 15) * 16 + (i >> 4)] = w1[i];
        if (tid < 16) xw[1040 + tid] = b1[tid];
    }
    half8_t B2f[8][2];
    {
        const half8_t* Fv = (const half8_t*)F2;
        #pragma unroll
        for (int s = 0; s < 8; ++s) {
            B2f[s][0] = Fv[(s * 2 + 0) * 64 + l];
            B2f[s][1] = Fv[(s * 2 + 1) * 64 + l];
        }
    }
    __syncthreads();

    {
        const float* xs  = xw;
        const float* w1s = xw + 784;
        const float* b1s = xw + 1040;
        const int p0 = tid, p1 = tid + 256;
        const bool v2 = (tid + 512) < 625;
        const int p2 = v2 ? tid + 512 : 624;
        const int y0 = p0 / 25, x0 = p0 % 25;
        const int y1 = p1 / 25, x1 = p1 % 25;
        const int y2 = p2 / 25, x2 = p2 % 25;
        float a0[16], a1[16], a2[16];
        #pragma unroll
        for (int oc = 0; oc < 16; ++oc) { const float bb = b1s[oc]; a0[oc] = bb; a1[oc] = bb; a2[oc] = bb; }
        #pragma unroll
        for (int k = 0; k < 16; ++k) {
            const int ky = k >> 2, kx = k & 3;
            const float i0 = xs[(y0 + ky) * 28 + x0 + kx];
            const float i1 = xs[(y1 + ky) * 28 + x1 + kx];
            const float i2 = xs[(y2 + ky) * 28 + x2 + kx];
            #pragma unroll
            for (int oc4 = 0; oc4 < 4; ++oc4) {
                const float4 wv = *(const float4*)&w1s[k * 16 + oc4 * 4];
                const float wq[4] = {wv.x, wv.y, wv.z, wv.w};
                #pragma unroll
                for (int q = 0; q < 4; ++q) {
                    const int oc = oc4 * 4 + q;
                    a0[oc] += i0 * wq[q]; a1[oc] += i1 * wq[q]; a2[oc] += i2 * wq[q];
                }
            }
        }
        #pragma unroll
        for (int i2_ = 0; i2_ < 8; ++i2_) {
            half2_t h0, h1;
            h0[0] = (half_t)fmaxf(a0[2 * i2_], 0.f); h0[1] = (half_t)fmaxf(a0[2 * i2_ + 1], 0.f);
            h1[0] = (half_t)fmaxf(a1[2 * i2_], 0.f); h1[1] = (half_t)fmaxf(a1[2 * i2_ + 1], 0.f);
            *(half2_t*)&plane1h[p0 * 16 + 2 * i2_] = h0;
            *(half2_t*)&plane1h[p1 * 16 + 2 * i2_] = h1;
        }
        if (v2) {
            #pragma unroll
            for (int i2_ = 0; i2_ < 8; ++i2_) {
                half2_t h2v;
                h2v[0] = (half_t)fmaxf(a2[2 * i2_], 0.f); h2v[1] = (half_t)fmaxf(a2[2 * i2_ + 1], 0.f);
                *(half2_t*)&plane1h[p2 * 16 + 2 * i2_] = h2v;
            }
        }
    }
    __syncthreads();

    {
        const float bias0 = b2[col];
        const float bias1 = (16 + col < 20) ? b2[16 + col] : 0.f;
        #pragma unroll 1
        for (int mt = wave; mt < 31; mt += 4) {
            const int pos = mt * 16 + col;
            const int py = pos / 22, px = pos - py * 22;
            const char* Ab = plane1b + (py * 25 + px) * 32 + g * 16;
            f32x4 c0 = {0.f, 0.f, 0.f, 0.f}, c1 = {0.f, 0.f, 0.f, 0.f};
            #pragma unroll
            for (int s = 0; s < 8; ++s) {
                const half8_t a = *(const half8_t*)(Ab + (s >> 1) * 800 + (s & 1) * 64);
                c0 = __builtin_amdgcn_mfma_f32_16x16x32_f16(a, B2f[s][0], c0, 0, 0, 0);
                c1 = __builtin_amdgcn_mfma_f32_16x16x32_f16(a, B2f[s][1], c1, 0, 0, 0);
            }
            #pragma unroll
            for (int r = 0; r < 4; ++r) {
                const int prow = mt * 16 + g * 4 + r;
                if (prow < 484) {
                    plane2h[prow * 24 + col] = (half_t)fmaxf(c0[r] + bias0, 0.f);
                    if (col < 8) {
                        const float v = (col < 4) ? fmaxf(c1[r] + bias1, 0.f) : 0.f;
                        plane2h[prow * 24 + 16 + col] = (half_t)v;
                    }
                }
            }
        }
    }
    half8_t B3f[12][2];
    {
        const half8_t* Fv = (const half8_t*)F3;
        #pragma unroll
        for (int s = 0; s < 12; ++s) {
            B3f[s][0] = Fv[(s * 2 + 0) * 64 + l];
            B3f[s][1] = Fv[(s * 2 + 1) * 64 + l];
        }
    }
    __syncthreads();

    {
        const float bias0 = b3[col];
        const float bias1 = b3[16 + (col & 7)];
        #pragma unroll 1
        for (int mt = wave; mt < 23; mt += 4) {
            const int pos = mt * 16 + col;
            const int py = pos / 19, px = pos - py * 19;
            const char* Ab = plane2b + (py * 22 + px) * 48 + g * 16;
            f32x4 c0 = {0.f, 0.f, 0.f, 0.f}, c1 = {0.f, 0.f, 0.f, 0.f};
            #pragma unroll
            for (int s = 0; s < 12; ++s) {
                const half8_t a = *(const half8_t*)(Ab + (s / 3) * 1056 + (s % 3) * 64);
                c0 = __builtin_amdgcn_mfma_f32_16x16x32_f16(a, B3f[s][0], c0, 0, 0, 0);
                c1 = __builtin_amdgcn_mfma_f32_16x16x32_f16(a, B3f[s][1], c1, 0, 0, 0);
            }
            #pragma unroll
            for (int r = 0; r < 4; ++r) {
                const int prow = mt * 16 + g * 4 + r;
                if (prow < 361) {
                    plane3h[prow * 24 + col] = (half_t)fmaxf(c0[r] + bias0, 0.f);
                    if (col < 8)
                        plane3h[prow * 24 + 16 + col] = (half_t)fmaxf(c1[r] + bias1, 0.f);
                }
            }
        }
    }
    half8_t B4f[12][2];
    {
        const half8_t* Fv = (const half8_t*)F4;
        #pragma unroll
        for (int s = 0; s < 12; ++s) {
            B4f[s][0] = Fv[(s * 2 + 0) * 64 + l];
            B4f[s][1] = Fv[(s * 2 + 1) * 64 + l];
        }
    }
    __syncthreads();

    {
        const float bias0 = b4[col];
        const float bias1 = (16 + col < 30) ? b4[16 + col] : 0.f;
        half_t* hb = hout + (size_t)b * 256 * 32;
        #pragma unroll 1
        for (int mt = wave; mt < 16; mt += 4) {
            const int pos = mt * 16 + col;
            const int py = pos >> 4, px = pos & 15;
            const char* Ab = plane1b + (py * 19 + px) * 48 + g * 16;
            f32x4 c0 = {0.f, 0.f, 0.f, 0.f}, c1 = {0.f, 0.f, 0.f, 0.f};
            #pragma unroll
            for (int s = 0; s < 12; ++s) {
                const half8_t a = *(const half8_t*)(Ab + (s / 3) * 912 + (s % 3) * 64);
                c0 = __builtin_amdgcn_mfma_f32_16x16x32_f16(a, B4f[s][0], c0, 0, 0, 0);
                c1 = __builtin_amdgcn_mfma_f32_16x16x32_f16(a, B4f[s][1], c1, 0, 0, 0);
            }
            #pragma unroll
            for (int r = 0; r < 4; ++r) {
                const int prow = mt * 16 + g * 4 + r;
                hb[prow * 32 + col] = (half_t)fmaxf(c0[r] + bias0, 0.f);
                if (col < 14)
                    hb[prow * 32 + 16 + col] = (half_t)fmaxf(c1[r] + bias1, 0.f);
            }
        }
        hb[tid * 32 + 30] = (half_t)((float)(tid & 15) * 0.0625f);
        hb[tid * 32 + 31] = (half_t)((float)(tid >> 4) * 0.0625f);
    }
}

// ===========================================================================
__device__ __forceinline__ void block_reduce2(float& s1, float& s2, float* red)
{
    #pragma unroll
    for (int off = 32; off > 0; off >>= 1) {
        s1 += __shfl_down(s1, off);
        s2 += __shfl_down(s2, off);
    }
    const int lane = threadIdx.x & 63;
    const int wid  = threadIdx.x >> 6;
    if (lane == 0) { red[wid * 2] = s1; red[wid * 2 + 1] = s2; }
    __syncthreads();
    s1 = red[0] + red[2] + red[4] + red[6];
    s2 = red[1] + red[3] + red[5] + red[7];
    __syncthreads();
}

// ===========================================================================
// Attention + head, full-MFMA version.
// LDS regions:
//   Qbuf [256][48] fp16 (24576B) : proj scratch -> Q rows -> att rows
//   Kbuf [256][48] fp16 (24576B) : K rows            (96B rows: frag reads conflict-free)
//   Vt   [48][256]  fp16 (24576B) : V^T, XOR-swizzled (halfidx ^ ((feat&7)<<2))
//   mbuf [256][36]  f32  (over Kbuf+Vt, epilogue max-reduction)
// ===========================================================================
__global__ __launch_bounds__(256, 2) void attn_head_kernel(
    const half_t* __restrict__ hbuf,
    const float* __restrict__ kW, const float* __restrict__ kb,
    const float* __restrict__ qW, const float* __restrict__ qb,
    const float* __restrict__ vW, const float* __restrict__ vb,
    const float* __restrict__ kg, const float* __restrict__ kbeta,
    const float* __restrict__ qg, const float* __restrict__ qbeta,
    const float* __restrict__ vg, const float* __restrict__ vbeta,
    const float* __restrict__ l1W, const float* __restrict__ l1b,
    const float* __restrict__ l2W, const float* __restrict__ l2b,
    float* __restrict__ out)
{
    __shared__ __attribute__((aligned(16))) char LDS[73728];
    __shared__ float red[8];
    half_t* Qbuf = (half_t*)LDS;
    half_t* Kbuf = (half_t*)(LDS + 24576);
    half_t* Vt   = (half_t*)(LDS + 49152);
    float*  mbuf = (float*)(LDS + 24576);

    const int b   = blockIdx.x;
    const int tid = threadIdx.x;
    const int w   = tid >> 6;
    const int l   = tid & 63;
    const int c   = l & 15;
    const int g   = l >> 4;

    // ---- h A-fragments (wave w owns node rows 64w..64w+63) ----
    half8_t hA[4];
    #pragma unroll
    for (int mt = 0; mt < 4; ++mt)
        hA[mt] = *(const half8_t*)(hbuf + ((size_t)b * 256 + 64 * w + 16 * mt + c) * 32 + 8 * g);

    // ---- three projections: K (0), V (1), Q (2) ----
    #pragma unroll 1
    for (int pj = 0; pj < 3; ++pj) {
        const float* W    = (pj == 0) ? kW : (pj == 1) ? vW : qW;
        const float* bias = (pj == 0) ? kb : (pj == 1) ? vb : qb;
        const float* gam  = (pj == 0) ? kg : (pj == 1) ? vg : qg;
        const float* bet  = (pj == 0) ? kbeta : (pj == 1) ? vbeta : qbeta;

        // B-fragments from W [36][32] f32 (rows >=36 zero-padded)
        half8_t Bf[3];
        #pragma unroll
        for (int nt = 0; nt < 3; ++nt) {
            const int row = 16 * nt + c;
            half8_t hb;
            if (row < 36) {
                const float4 w0 = *(const float4*)(W + row * 32 + 8 * g);
                const float4 w1 = *(const float4*)(W + row * 32 + 8 * g + 4);
                hb[0] = (half_t)w0.x; hb[1] = (half_t)w0.y; hb[2] = (half_t)w0.z; hb[3] = (half_t)w0.w;
                hb[4] = (half_t)w1.x; hb[5] = (half_t)w1.y; hb[6] = (half_t)w1.z; hb[7] = (half_t)w1.w;
            } else {
                #pragma unroll
                for (int j = 0; j < 8; ++j) hb[j] = (half_t)0.f;
            }
            Bf[nt] = hb;
        }
        // C init = bias (same for all rows of a column)
        f32x4 acc[4][3];
        #pragma unroll
        for (int nt = 0; nt < 3; ++nt) {
            const int o = 16 * nt + c;
            const float bv = (o < 36) ? bias[o] : 0.f;
            #pragma unroll
            for (int mt = 0; mt < 4; ++mt) acc[mt][nt] = (f32x4){bv, bv, bv, bv};
        }
        #pragma unroll
        for (int mt = 0; mt < 4; ++mt)
            #pragma unroll
            for (int nt = 0; nt < 3; ++nt)
                acc[mt][nt] = __builtin_amdgcn_mfma_f32_16x16x32_f16(hA[mt], Bf[nt], acc[mt][nt], 0, 0, 0);

        // scatter C -> scratch [node][feat48]
        #pragma unroll
        for (int mt = 0; mt < 4; ++mt)
            #pragma unroll
            for (int nt = 0; nt < 3; ++nt)
                #pragma unroll
                for (int r = 0; r < 4; ++r)
                    Qbuf[(64 * w + 16 * mt + 4 * g + r) * 48 + 16 * nt + c] = (half_t)acc[mt][nt][r];
        __syncthreads();

        // per-node joint LayerNorm (thread = node)
        float rv[36];
        {
            const half_t* rp = Qbuf + tid * 48;
            #pragma unroll
            for (int j = 0; j < 36; ++j) rv[j] = (float)rp[j];
        }
        float s1 = 0.f, s2 = 0.f;
        #pragma unroll
        for (int j = 0; j < 36; ++j) { s1 += rv[j]; s2 += rv[j] * rv[j]; }
        block_reduce2(s1, s2, red);
        const float mu  = s1 * (1.0f / 9216.0f);
        const float var = s2 * (1.0f / 9216.0f) - mu * mu;
        const float rs  = rsqrtf(var + LN_EPS);

        half_t rowb[48];
        #pragma unroll
        for (int j4 = 0; j4 < 9; ++j4) {
            const float4 gm = *(const float4*)(gam + tid * 36 + 4 * j4);
            const float4 bt = *(const float4*)(bet + tid * 36 + 4 * j4);
            float f0 = (rv[4*j4+0] - mu) * rs * gm.x + bt.x;
            float f1 = (rv[4*j4+1] - mu) * rs * gm.y + bt.y;
            float f2 = (rv[4*j4+2] - mu) * rs * gm.z + bt.z;
            float f3 = (rv[4*j4+3] - mu) * rs * gm.w + bt.w;
            if (pj == 2) { f0 *= (1.0f/6.0f); f1 *= (1.0f/6.0f); f2 *= (1.0f/6.0f); f3 *= (1.0f/6.0f); }
            rowb[4*j4+0] = (half_t)f0; rowb[4*j4+1] = (half_t)f1;
            rowb[4*j4+2] = (half_t)f2; rowb[4*j4+3] = (half_t)f3;
        }
        #pragma unroll
        for (int j = 36; j < 48; ++j) rowb[j] = (half_t)0.f;

        if (pj == 0) {
            #pragma unroll
            for (int i = 0; i < 6; ++i)
                *(half8_t*)(Kbuf + tid * 48 + 8 * i) = *(half8_t*)&rowb[8 * i];
        } else if (pj == 1) {
            #pragma unroll
            for (int j = 0; j < 36; ++j)
                Vt[j * 256 + (tid ^ ((j & 7) << 2))] = rowb[j];
        } else {
            #pragma unroll
            for (int i = 0; i < 6; ++i)
                *(half8_t*)(Qbuf + tid * 48 + 8 * i) = *(half8_t*)&rowb[8 * i];
        }
        __syncthreads();
    }

    // ---- Q fragments (wave-local rows), held in registers ----
    half8_t Qf32[4];
    half4_t Qf16[4];
    #pragma unroll
    for (int nt = 0; nt < 4; ++nt) {
        const int row = 64 * w + 16 * nt + c;
        Qf32[nt] = *(const half8_t*)(Qbuf + row * 48 + 8 * g);
        Qf16[nt] = *(const half4_t*)(Qbuf + row * 48 + 32 + 4 * g);
    }

    // ---- kv-loop: 8 chunks x 32 keys, no barriers ----
    float m[4], lsum[4];
    f32x4 att[3][4];
    #pragma unroll
    for (int nt = 0; nt < 4; ++nt) {
        m[nt] = -1e30f; lsum[nt] = 0.f;
        #pragma unroll
        for (int mt2 = 0; mt2 < 3; ++mt2) att[mt2][nt] = (f32x4){0.f, 0.f, 0.f, 0.f};
    }

    #pragma unroll 1
    for (int ch = 0; ch < 8; ++ch) {
        half8_t Ka32[2];
        half4_t Ka16[2];
        #pragma unroll
        for (int mt = 0; mt < 2; ++mt) {
            const int row = 32 * ch + 16 * mt + c;
            Ka32[mt] = *(const half8_t*)(Kbuf + row * 48 + 8 * g);
            Ka16[mt] = *(const half4_t*)(Kbuf + row * 48 + 32 + 4 * g);
        }
        half4_t Va[3][2];
        #pragma unroll
        for (int mt2 = 0; mt2 < 3; ++mt2)
            #pragma unroll
            for (int kc = 0; kc < 2; ++kc)
                Va[mt2][kc] = *(const half4_t*)(Vt + (16 * mt2 + c) * 256 +
                                ((32 * ch + 16 * kc + 4 * g) ^ ((c & 7) << 2)));

        // S^T chunk: rows = keys, cols = qrows
        f32x4 S[2][4];
        #pragma unroll
        for (int mt = 0; mt < 2; ++mt)
            #pragma unroll
            for (int nt = 0; nt < 4; ++nt) {
                f32x4 z = {0.f, 0.f, 0.f, 0.f};
                z = __builtin_amdgcn_mfma_f32_16x16x32_f16(Ka32[mt], Qf32[nt], z, 0, 0, 0);
                z = __builtin_amdgcn_mfma_f32_16x16x16f16(Ka16[mt], Qf16[nt], z, 0, 0, 0);
                S[mt][nt] = z;
            }

        // online softmax + PV per qrow-tile
        #pragma unroll
        for (int nt = 0; nt < 4; ++nt) {
            float cm = S[0][nt][0];
            cm = fmaxf(cm, S[0][nt][1]); cm = fmaxf(cm, S[0][nt][2]); cm = fmaxf(cm, S[0][nt][3]);
            cm = fmaxf(cm, S[1][nt][0]); cm = fmaxf(cm, S[1][nt][1]);
            cm = fmaxf(cm, S[1][nt][2]); cm = fmaxf(cm, S[1][nt][3]);
            cm = fmaxf(cm, __shfl_xor(cm, 16));
            cm = fmaxf(cm, __shfl_xor(cm, 32));
            const float newm  = fmaxf(m[nt], cm);
            const float alpha = __expf(m[nt] - newm);
            m[nt] = newm;
            lsum[nt] *= alpha;
            #pragma unroll
            for (int mt2 = 0; mt2 < 3; ++mt2) att[mt2][nt] *= alpha;

            half4_t P[2];
            #pragma unroll
            for (int mt = 0; mt < 2; ++mt) {
                const float p0 = __expf(S[mt][nt][0] - newm);
                const float p1 = __expf(S[mt][nt][1] - newm);
                const float p2 = __expf(S[mt][nt][2] - newm);
                const float p3 = __expf(S[mt][nt][3] - newm);
                lsum[nt] += (p0 + p1) + (p2 + p3);
                half4_t pp;
                pp[0] = (half_t)p0; pp[1] = (half_t)p1; pp[2] = (half_t)p2; pp[3] = (half_t)p3;
                P[mt] = pp;
            }
            #pragma unroll
            for (int mt2 = 0; mt2 < 3; ++mt2) {
                att[mt2][nt] = __builtin_amdgcn_mfma_f32_16x16x16f16(Va[mt2][0], P[0], att[mt2][nt], 0, 0, 0);
                att[mt2][nt] = __builtin_amdgcn_mfma_f32_16x16x16f16(Va[mt2][1], P[1], att[mt2][nt], 0, 0, 0);
            }
        }
    }

    // ---- finalize: divide by l, write att rows (feat<36) to Qbuf ----
    #pragma unroll
    for (int nt = 0; nt < 4; ++nt) {
        float lt = lsum[nt];
        lt += __shfl_xor(lt, 16);
        lt += __shfl_xor(lt, 32);
        const float inv = 1.0f / lt;
        const int row = 64 * w + 16 * nt + c;
        #pragma unroll
        for (int mt2 = 0; mt2 < 2; ++mt2)
            #pragma unroll
            for (int r = 0; r < 4; ++r)
                Qbuf[row * 48 + 16 * mt2 + 4 * g + r] = (half_t)(att[mt2][nt][r] * inv);
        if (g == 0) {
            #pragma unroll
            for (int r = 0; r < 4; ++r)
                Qbuf[row * 48 + 32 + r] = (half_t)(att[2][nt][r] * inv);
        }
    }
    __syncthreads();

    // ---- epilogue: l1+ReLU, joint LN (no affine), node-max, head ----
    float at[36];
    #pragma unroll
    for (int j = 0; j < 36; ++j) at[j] = (float)Qbuf[tid * 48 + j];

    float a2[36];
    #pragma unroll
    for (int jj = 0; jj < 36; ++jj) {
        float s = l1b[jj];
        #pragma unroll
        for (int d = 0; d < 36; ++d) s += at[d] * l1W[jj * 36 + d];
        a2[jj] = fmaxf(s, 0.f);
    }

    float s1 = 0.f, s2 = 0.f;
    #pragma unroll
    for (int j = 0; j < 36; ++j) { s1 += a2[j]; s2 += a2[j] * a2[j]; }
    block_reduce2(s1, s2, red);
    const float mu  = s1 * (1.0f / 9216.0f);
    const float var = s2 * (1.0f / 9216.0f) - mu * mu;
    const float rs  = rsqrtf(var + LN_EPS);

    #pragma unroll
    for (int j4 = 0; j4 < 9; ++j4) {
        float4 t;
        t.x = (a2[4*j4+0] - mu) * rs; t.y = (a2[4*j4+1] - mu) * rs;
        t.z = (a2[4*j4+2] - mu) * rs; t.w = (a2[4*j4+3] - mu) * rs;
        *((float4*)&mbuf[tid * 36 + 4 * j4]) = t;
    }
    __syncthreads();

    #pragma unroll 1
    for (int stride = 128; stride >= 1; stride >>= 1) {
        if (tid < stride) {
            #pragma unroll
            for (int j = 0; j < 36; ++j)
                mbuf[tid * 36 + j] = fmaxf(mbuf[tid * 36 + j], mbuf[(tid + stride) * 36 + j]);
        }
        __syncthreads();
    }

    if (tid == 0) {
        float y[10];
        #pragma unroll
        for (int cc = 0; cc < 10; ++cc) {
            float s = l2b[cc];
            #pragma unroll
            for (int j = 0; j < 36; ++j) s += mbuf[j] * l2W[cc * 36 + j];
            y[cc] = s;
        }
        float mx = y[0];
        #pragma unroll
        for (int cc = 1; cc < 10; ++cc) mx = fmaxf(mx, y[cc]);
        float se = 0.f;
        #pragma unroll
        for (int cc = 0; cc < 10; ++cc) se += __expf(y[cc] - mx);
        const float lse = mx + logf(se);
        #pragma unroll
        for (int cc = 0; cc < 10; ++cc) out[b * 10 + cc] = y[cc] - lse;
    }
}

// ===========================================================================
extern "C" void kernel_launch(void* const* d_in, const int* in_sizes, int n_in,
                              void* d_out, int out_size, void* d_ws, size_t ws_size,
                              hipStream_t stream)
{
    const float* x     = (const float*)d_in[0];
    const float* w1    = (const float*)d_in[1];
    const float* b1    = (const float*)d_in[2];
    const float* w2    = (const float*)d_in[3];
    const float* b2    = (const float*)d_in[4];
    const float* w3    = (const float*)d_in[5];
    const float* b3    = (const float*)d_in[6];
    const float* w4    = (const float*)d_in[7];
    const float* b4    = (const float*)d_in[8];
    const float* kW    = (const float*)d_in[9];
    const float* kb    = (const float*)d_in[10];
    const float* qW    = (const float*)d_in[11];
    const float* qb    = (const float*)d_in[12];
    const float* vW    = (const float*)d_in[13];
    const float* vb    = (const float*)d_in[14];
    const float* kg    = (const float*)d_in[15];
    const float* kbeta = (const float*)d_in[16];
    const float* qg    = (const float*)d_in[17];
    const float* qbeta = (const float*)d_in[18];
    const float* vg    = (const float*)d_in[19];
    const float* vbeta = (const float*)d_in[20];
    const float* l1W   = (const float*)d_in[21];
    const float* l1b   = (const float*)d_in[22];
    const float* l2W   = (const float*)d_in[23];
    const float* l2b   = (const float*)d_in[24];

    const int B = in_sizes[0] / (28 * 28);            // 2048
    half_t* hbuf = (half_t*)d_ws;                     // [B,256,32] fp16 = 33.5 MB
    half_t* F2 = (half_t*)((char*)d_ws + 33554432);
    half_t* F3 = F2 + 8192;
    half_t* F4 = F3 + 12288;

    prep_weights_kernel<<<dim3(64), dim3(256), 0, stream>>>(w2, w3, w4, F2, F3, F4);
    conv_fused_kernel<<<dim3(B), dim3(256), 0, stream>>>(
        x, w1, b1, b2, b3, b4, F2, F3, F4, hbuf);
    attn_head_kernel<<<dim3(B), dim3(256), 0, stream>>>(
        hbuf, kW, kb, qW, qb, vW, vb,
        kg, kbeta, qg, qbeta, vg, vbeta,
        l1W, l1b, l2W, l2b, (float*)d_out);
}

// Round 4
// 293.981 us; speedup vs baseline: 10.2019x; 1.3181x over previous
//
#include <hip/hip_runtime.h>
#include <math.h>

#define LN_EPS 1e-5f

typedef _Float16 half_t;
typedef _Float16 half8_t __attribute__((ext_vector_type(8)));
typedef _Float16 half4_t __attribute__((ext_vector_type(4)));
typedef _Float16 half2_t __attribute__((ext_vector_type(2)));
typedef float f32x4 __attribute__((ext_vector_type(4)));

// ===========================================================================
// Weight-prep: reorder conv weights into MFMA B-fragment order (fp16).
// ===========================================================================
__global__ void prep_weights_kernel(const float* __restrict__ w2,
                                    const float* __restrict__ w3,
                                    const float* __restrict__ w4,
                                    half_t* __restrict__ F2,
                                    half_t* __restrict__ F3,
                                    half_t* __restrict__ F4)
{
    const int bid = blockIdx.x;
    const int t   = threadIdx.x;
    const int flat0 = t * 2;
    const int l  = flat0 >> 3;
    const int j0 = flat0 & 7;

    int layer, sn;
    half_t* dst;
    if (bid < 16)      { layer = 2; sn = bid;      dst = F2; }
    else if (bid < 40) { layer = 3; sn = bid - 16; dst = F3; }
    else               { layer = 4; sn = bid - 40; dst = F4; }
    const int s  = sn >> 1;
    const int nt = sn & 1;
    const int oc = nt * 16 + (l & 15);

    float v[2];
    #pragma unroll
    for (int u = 0; u < 2; ++u) {
        const int j = j0 + u;
        const int k = s * 32 + ((l >> 4) * 8) + j;
        float val = 0.f;
        if (layer == 2) {
            const int ky = k >> 6, rem = k & 63, kx = rem >> 4, ic = rem & 15;
            if (oc < 20) val = w2[(oc * 16 + ic) * 16 + ky * 4 + kx];
        } else if (layer == 3) {
            const int ky = k / 96, rem = k % 96, kx = rem / 24, ic = rem % 24;
            if (oc < 24 && ic < 20) val = w3[(oc * 20 + ic) * 16 + ky * 4 + kx];
        } else {
            const int ky = k / 96, rem = k % 96, kx = rem / 24, ic = rem % 24;
            if (oc < 30) val = w4[(oc * 24 + ic) * 16 + ky * 4 + kx];
        }
        v[u] = val;
    }
    half2_t outv;
    outv[0] = (half_t)v[0];
    outv[1] = (half_t)v[1];
    *(half2_t*)&dst[(sn * 64 + l) * 8 + j0] = outv;
}

// ===========================================================================
// Fused conv stack, MFMA implicit GEMM.
// B-fragments loaded per-stage (no cross-stage register residency -> no spill).
// conv4 output staged in LDS, then coalesced float4 global writes.
// ===========================================================================
__global__ __launch_bounds__(256, 2) void conv_fused_kernel(
    const float* __restrict__ x,
    const float* __restrict__ w1, const float* __restrict__ b1,
    const float* __restrict__ b2, const float* __restrict__ b3,
    const float* __restrict__ b4,
    const half_t* __restrict__ F2, const half_t* __restrict__ F3,
    const half_t* __restrict__ F4,
    half_t* __restrict__ hout)
{
    __shared__ __attribute__((aligned(16))) char LBUF[45280];
    float*  xw = (float*)LBUF;
    char*   plane2b = LBUF;                 // conv2 out / conv4 stage region
    char*   plane1b = LBUF + 23232;         // conv1 out / conv3 out region
    half_t* plane2h = (half_t*)plane2b;
    half_t* plane1h = (half_t*)plane1b;
    half_t* plane3h = (half_t*)plane1b;
    half_t* stage   = (half_t*)plane2b;     // conv4 staging [256][32] fp16

    const int b    = blockIdx.x;
    const int tid  = threadIdx.x;
    const int wave = tid >> 6;
    const int l    = tid & 63;
    const int col  = l & 15;
    const int g    = l >> 4;

    {
        const float4* gx = (const float4*)(x + (size_t)b * 784);
        if (tid < 196) ((float4*)xw)[tid] = gx[tid];
        const int i = tid;
        if (i < 256) xw[784 + (i & 15) * 16 + (i >> 4)] = w1[i];
        if (tid < 16) xw[1040 + tid] = b1[tid];
    }
    __syncthreads();

    // ---- conv1 (fp32 VALU): 1->16, 28x28 -> 25x25, HWC fp16 out ----
    {
        const float* xs  = xw;
        const float* w1s = xw + 784;
        const float* b1s = xw + 1040;
        const int p0 = tid, p1 = tid + 256;
        const bool v2 = (tid + 512) < 625;
        const int p2 = v2 ? tid + 512 : 624;
        const int y0 = p0 / 25, x0 = p0 % 25;
        const int y1 = p1 / 25, x1 = p1 % 25;
        const int y2 = p2 / 25, x2 = p2 % 25;
        float a0[16], a1[16], a2[16];
        #pragma unroll
        for (int oc = 0; oc < 16; ++oc) { const float bb = b1s[oc]; a0[oc] = bb; a1[oc] = bb; a2[oc] = bb; }
        #pragma unroll
        for (int k = 0; k < 16; ++k) {
            const int ky = k >> 2, kx = k & 3;
            const float i0 = xs[(y0 + ky) * 28 + x0 + kx];
            const float i1 = xs[(y1 + ky) * 28 + x1 + kx];
            const float i2 = xs[(y2 + ky) * 28 + x2 + kx];
            #pragma unroll
            for (int oc4 = 0; oc4 < 4; ++oc4) {
                const float4 wv = *(const float4*)&w1s[k * 16 + oc4 * 4];
                const float wq[4] = {wv.x, wv.y, wv.z, wv.w};
                #pragma unroll
                for (int q = 0; q < 4; ++q) {
                    const int oc = oc4 * 4 + q;
                    a0[oc] += i0 * wq[q]; a1[oc] += i1 * wq[q]; a2[oc] += i2 * wq[q];
                }
            }
        }
        __syncthreads();   // xw reads done before plane1 writes overlap region? (disjoint, but cheap safety for x region reuse ordering)
        #pragma unroll
        for (int i2_ = 0; i2_ < 8; ++i2_) {
            half2_t h0, h1;
            h0[0] = (half_t)fmaxf(a0[2 * i2_], 0.f); h0[1] = (half_t)fmaxf(a0[2 * i2_ + 1], 0.f);
            h1[0] = (half_t)fmaxf(a1[2 * i2_], 0.f); h1[1] = (half_t)fmaxf(a1[2 * i2_ + 1], 0.f);
            *(half2_t*)&plane1h[p0 * 16 + 2 * i2_] = h0;
            *(half2_t*)&plane1h[p1 * 16 + 2 * i2_] = h1;
        }
        if (v2) {
            #pragma unroll
            for (int i2_ = 0; i2_ < 8; ++i2_) {
                half2_t h2v;
                h2v[0] = (half_t)fmaxf(a2[2 * i2_], 0.f); h2v[1] = (half_t)fmaxf(a2[2 * i2_ + 1], 0.f);
                *(half2_t*)&plane1h[p2 * 16 + 2 * i2_] = h2v;
            }
        }
    }
    __syncthreads();

    // ---- conv2 (MFMA): 16->20(pad24), 25x25 -> 22x22, K=256 (8 steps) ----
    {
        half8_t B2f[8][2];                       // loaded HERE (stage-local)
        const half8_t* Fv = (const half8_t*)F2;
        #pragma unroll
        for (int s = 0; s < 8; ++s) {
            B2f[s][0] = Fv[(s * 2 + 0) * 64 + l];
            B2f[s][1] = Fv[(s * 2 + 1) * 64 + l];
        }
        const float bias0 = b2[col];
        const float bias1 = (16 + col < 20) ? b2[16 + col] : 0.f;
        #pragma unroll 1
        for (int mt = wave; mt < 31; mt += 4) {
            const int pos = mt * 16 + col;
            const int py = pos / 22, px = pos - py * 22;
            const char* Ab = plane1b + (py * 25 + px) * 32 + g * 16;
            f32x4 c0 = {0.f, 0.f, 0.f, 0.f}, c1 = {0.f, 0.f, 0.f, 0.f};
            #pragma unroll
            for (int s = 0; s < 8; ++s) {
                const half8_t a = *(const half8_t*)(Ab + (s >> 1) * 800 + (s & 1) * 64);
                c0 = __builtin_amdgcn_mfma_f32_16x16x32_f16(a, B2f[s][0], c0, 0, 0, 0);
                c1 = __builtin_amdgcn_mfma_f32_16x16x32_f16(a, B2f[s][1], c1, 0, 0, 0);
            }
            #pragma unroll
            for (int r = 0; r < 4; ++r) {
                const int prow = mt * 16 + g * 4 + r;
                if (prow < 484) {
                    plane2h[prow * 24 + col] = (half_t)fmaxf(c0[r] + bias0, 0.f);
                    if (col < 8) {
                        const float v = (col < 4) ? fmaxf(c1[r] + bias1, 0.f) : 0.f;
                        plane2h[prow * 24 + 16 + col] = (half_t)v;
                    }
                }
            }
        }
    }
    __syncthreads();

    // ---- conv3 (MFMA): 24(in,pad)->24, 22x22 -> 19x19, K=384 (12 steps) ----
    {
        half8_t B3f[12][2];                      // loaded HERE
        const half8_t* Fv = (const half8_t*)F3;
        #pragma unroll
        for (int s = 0; s < 12; ++s) {
            B3f[s][0] = Fv[(s * 2 + 0) * 64 + l];
            B3f[s][1] = Fv[(s * 2 + 1) * 64 + l];
        }
        const float bias0 = b3[col];
        const float bias1 = b3[16 + (col & 7)];
        #pragma unroll 1
        for (int mt = wave; mt < 23; mt += 4) {
            const int pos = mt * 16 + col;
            const int py = pos / 19, px = pos - py * 19;
            const char* Ab = plane2b + (py * 22 + px) * 48 + g * 16;
            f32x4 c0 = {0.f, 0.f, 0.f, 0.f}, c1 = {0.f, 0.f, 0.f, 0.f};
            #pragma unroll
            for (int s = 0; s < 12; ++s) {
                const half8_t a = *(const half8_t*)(Ab + (s / 3) * 1056 + (s % 3) * 64);
                c0 = __builtin_amdgcn_mfma_f32_16x16x32_f16(a, B3f[s][0], c0, 0, 0, 0);
                c1 = __builtin_amdgcn_mfma_f32_16x16x32_f16(a, B3f[s][1], c1, 0, 0, 0);
            }
            #pragma unroll
            for (int r = 0; r < 4; ++r) {
                const int prow = mt * 16 + g * 4 + r;
                if (prow < 361) {
                    plane3h[prow * 24 + col] = (half_t)fmaxf(c0[r] + bias0, 0.f);
                    if (col < 8)
                        plane3h[prow * 24 + 16 + col] = (half_t)fmaxf(c1[r] + bias1, 0.f);
                }
            }
        }
    }
    __syncthreads();

    // ---- conv4 (MFMA): 24->30, 19x19 -> 16x16; stage in LDS ----
    {
        half8_t B4f[12][2];                      // loaded HERE
        const half8_t* Fv = (const half8_t*)F4;
        #pragma unroll
        for (int s = 0; s < 12; ++s) {
            B4f[s][0] = Fv[(s * 2 + 0) * 64 + l];
            B4f[s][1] = Fv[(s * 2 + 1) * 64 + l];
        }
        const float bias0 = b4[col];
        const float bias1 = (16 + col < 30) ? b4[16 + col] : 0.f;
        #pragma unroll 1
        for (int mt = wave; mt < 16; mt += 4) {
            const int pos = mt * 16 + col;
            const int py = pos >> 4, px = pos & 15;
            const char* Ab = plane1b + (py * 19 + px) * 48 + g * 16;   // plane3
            f32x4 c0 = {0.f, 0.f, 0.f, 0.f}, c1 = {0.f, 0.f, 0.f, 0.f};
            #pragma unroll
            for (int s = 0; s < 12; ++s) {
                const half8_t a = *(const half8_t*)(Ab + (s / 3) * 912 + (s % 3) * 64);
                c0 = __builtin_amdgcn_mfma_f32_16x16x32_f16(a, B4f[s][0], c0, 0, 0, 0);
                c1 = __builtin_amdgcn_mfma_f32_16x16x32_f16(a, B4f[s][1], c1, 0, 0, 0);
            }
            #pragma unroll
            for (int r = 0; r < 4; ++r) {
                const int prow = mt * 16 + g * 4 + r;   // < 256
                stage[prow * 32 + col] = (half_t)fmaxf(c0[r] + bias0, 0.f);
                if (col < 14)
                    stage[prow * 32 + 16 + col] = (half_t)fmaxf(c1[r] + bias1, 0.f);
            }
        }
        // coord channels (half2 per thread)
        half2_t cc;
        cc[0] = (half_t)((float)(tid & 15) * 0.0625f);
        cc[1] = (half_t)((float)(tid >> 4) * 0.0625f);
        *(half2_t*)&stage[tid * 32 + 30] = cc;
    }
    __syncthreads();

    // ---- coalesced copy LDS stage -> hbuf (full 64B lines) ----
    {
        const float4* sst  = (const float4*)stage;
        float4* gdst = (float4*)(hout + (size_t)b * 8192);
        #pragma unroll
        for (int k2 = 0; k2 < 4; ++k2)
            gdst[tid + 256 * k2] = sst[tid + 256 * k2];
    }
}

// ===========================================================================
__device__ __forceinline__ void block_reduce2(float& s1, float& s2, float* red)
{
    #pragma unroll
    for (int off = 32; off > 0; off >>= 1) {
        s1 += __shfl_down(s1, off);
        s2 += __shfl_down(s2, off);
    }
    const int lane = threadIdx.x & 63;
    const int wid  = threadIdx.x >> 6;
    if (lane == 0) { red[wid * 2] = s1; red[wid * 2 + 1] = s2; }
    __syncthreads();
    s1 = red[0] + red[2] + red[4] + red[6];
    s2 = red[1] + red[3] + red[5] + red[7];
    __syncthreads();
}

__device__ __forceinline__ void block_reduce6(float* s, float* red)
{
    #pragma unroll
    for (int off = 32; off > 0; off >>= 1)
        #pragma unroll
        for (int i = 0; i < 6; ++i) s[i] += __shfl_down(s[i], off);
    const int lane = threadIdx.x & 63;
    const int wid  = threadIdx.x >> 6;
    if (lane == 0) {
        #pragma unroll
        for (int i = 0; i < 6; ++i) red[wid * 6 + i] = s[i];
    }
    __syncthreads();
    #pragma unroll
    for (int i = 0; i < 6; ++i)
        s[i] = red[i] + red[6 + i] + red[12 + i] + red[18 + i];
    __syncthreads();
}

// ===========================================================================
// Attention + head, full-MFMA, merged single-pass projections.
// LDS: Qbuf[256][48] | Kbuf[256][48] | Vbuf[256][48] (-> Vt[48][256] swizzled)
// ===========================================================================
__global__ __launch_bounds__(256, 2) void attn_head_kernel(
    const half_t* __restrict__ hbuf,
    const float* __restrict__ kW, const float* __restrict__ kb,
    const float* __restrict__ qW, const float* __restrict__ qb,
    const float* __restrict__ vW, const float* __restrict__ vb,
    const float* __restrict__ kg, const float* __restrict__ kbeta,
    const float* __restrict__ qg, const float* __restrict__ qbeta,
    const float* __restrict__ vg, const float* __restrict__ vbeta,
    const float* __restrict__ l1W, const float* __restrict__ l1b,
    const float* __restrict__ l2W, const float* __restrict__ l2b,
    float* __restrict__ out)
{
    __shared__ __attribute__((aligned(16))) char LDS[73728];
    __shared__ float red[24];
    __shared__ float epi[196];     // 4*36 wave-max + 36 final + 10 y + lse

    half_t* Qbuf = (half_t*)LDS;
    half_t* Kbuf = (half_t*)(LDS + 24576);
    half_t* Vbuf = (half_t*)(LDS + 49152);
    half_t* Vt   = Vbuf;

    const int b   = blockIdx.x;
    const int tid = threadIdx.x;
    const int w   = tid >> 6;
    const int l   = tid & 63;
    const int c   = l & 15;
    const int g   = l >> 4;

    // ---- h A-fragments ----
    half8_t hA[4];
    #pragma unroll
    for (int mt = 0; mt < 4; ++mt)
        hA[mt] = *(const half8_t*)(hbuf + ((size_t)b * 256 + 64 * w + 16 * mt + c) * 32 + 8 * g);

    // ---- three projection GEMMs, no barriers between ----
    #pragma unroll 1
    for (int pj = 0; pj < 3; ++pj) {
        const float* W    = (pj == 0) ? kW : (pj == 1) ? vW : qW;
        const float* bias = (pj == 0) ? kb : (pj == 1) ? vb : qb;
        half_t* scr       = (pj == 0) ? Kbuf : (pj == 1) ? Vbuf : Qbuf;

        half8_t Bf[3];
        #pragma unroll
        for (int nt = 0; nt < 3; ++nt) {
            const int row = 16 * nt + c;
            half8_t hb;
            if (row < 36) {
                const float4 w0 = *(const float4*)(W + row * 32 + 8 * g);
                const float4 w1 = *(const float4*)(W + row * 32 + 8 * g + 4);
                hb[0] = (half_t)w0.x; hb[1] = (half_t)w0.y; hb[2] = (half_t)w0.z; hb[3] = (half_t)w0.w;
                hb[4] = (half_t)w1.x; hb[5] = (half_t)w1.y; hb[6] = (half_t)w1.z; hb[7] = (half_t)w1.w;
            } else {
                #pragma unroll
                for (int j = 0; j < 8; ++j) hb[j] = (half_t)0.f;
            }
            Bf[nt] = hb;
        }
        f32x4 acc[4][3];
        #pragma unroll
        for (int nt = 0; nt < 3; ++nt) {
            const int o = 16 * nt + c;
            const float bv = (o < 36) ? bias[o] : 0.f;
            #pragma unroll
            for (int mt = 0; mt < 4; ++mt) acc[mt][nt] = (f32x4){bv, bv, bv, bv};
        }
        #pragma unroll
        for (int mt = 0; mt < 4; ++mt)
            #pragma unroll
            for (int nt = 0; nt < 3; ++nt)
                acc[mt][nt] = __builtin_amdgcn_mfma_f32_16x16x32_f16(hA[mt], Bf[nt], acc[mt][nt], 0, 0, 0);
        #pragma unroll
        for (int mt = 0; mt < 4; ++mt)
            #pragma unroll
            for (int nt = 0; nt < 3; ++nt)
                #pragma unroll
                for (int r = 0; r < 4; ++r)
                    scr[(64 * w + 16 * mt + 4 * g + r) * 48 + 16 * nt + c] = (half_t)acc[mt][nt][r];
    }
    __syncthreads();

    // ---- LN sums for all three (V row kept in registers) ----
    float sv[6];
    #pragma unroll
    for (int i = 0; i < 6; ++i) sv[i] = 0.f;
    {
        const half_t* rp = Kbuf + tid * 48;
        #pragma unroll
        for (int j = 0; j < 36; ++j) { const float v = (float)rp[j]; sv[0] += v; sv[1] += v * v; }
    }
    float rvV[36];
    {
        const half_t* rp = Vbuf + tid * 48;
        #pragma unroll
        for (int j = 0; j < 36; ++j) { const float v = (float)rp[j]; rvV[j] = v; sv[2] += v; sv[3] += v * v; }
    }
    {
        const half_t* rp = Qbuf + tid * 48;
        #pragma unroll
        for (int j = 0; j < 36; ++j) { const float v = (float)rp[j]; sv[4] += v; sv[5] += v * v; }
    }
    block_reduce6(sv, red);   // 2 barriers; also fences all scratch reads

    const float muK = sv[0] * (1.0f / 9216.0f);
    const float rsK = rsqrtf(sv[1] * (1.0f / 9216.0f) - muK * muK + LN_EPS);
    const float muV = sv[2] * (1.0f / 9216.0f);
    const float rsV = rsqrtf(sv[3] * (1.0f / 9216.0f) - muV * muV + LN_EPS);
    const float muQ = sv[4] * (1.0f / 9216.0f);
    const float rsQ = rsqrtf(sv[5] * (1.0f / 9216.0f) - muQ * muQ + LN_EPS);

    // ---- V: normalize from registers, write transposed+swizzled (rows 36-47 zeroed) ----
    {
        half_t rowb[36];
        #pragma unroll
        for (int j4 = 0; j4 < 9; ++j4) {
            const float4 gm = *(const float4*)(vg + tid * 36 + 4 * j4);
            const float4 bt = *(const float4*)(vbeta + tid * 36 + 4 * j4);
            rowb[4*j4+0] = (half_t)((rvV[4*j4+0] - muV) * rsV * gm.x + bt.x);
            rowb[4*j4+1] = (half_t)((rvV[4*j4+1] - muV) * rsV * gm.y + bt.y);
            rowb[4*j4+2] = (half_t)((rvV[4*j4+2] - muV) * rsV * gm.z + bt.z);
            rowb[4*j4+3] = (half_t)((rvV[4*j4+3] - muV) * rsV * gm.w + bt.w);
        }
        #pragma unroll
        for (int j = 0; j < 48; ++j) {
            const half_t v = (j < 36) ? rowb[j] : (half_t)0.f;
            Vt[j * 256 + (tid ^ ((j & 7) << 2))] = v;
        }
    }
    // ---- K: re-read own row, normalize in place ----
    {
        float rv[36];
        const half_t* rp = Kbuf + tid * 48;
        #pragma unroll
        for (int j = 0; j < 36; ++j) rv[j] = (float)rp[j];
        half_t rowb[48];
        #pragma unroll
        for (int j4 = 0; j4 < 9; ++j4) {
            const float4 gm = *(const float4*)(kg + tid * 36 + 4 * j4);
            const float4 bt = *(const float4*)(kbeta + tid * 36 + 4 * j4);
            rowb[4*j4+0] = (half_t)((rv[4*j4+0] - muK) * rsK * gm.x + bt.x);
            rowb[4*j4+1] = (half_t)((rv[4*j4+1] - muK) * rsK * gm.y + bt.y);
            rowb[4*j4+2] = (half_t)((rv[4*j4+2] - muK) * rsK * gm.z + bt.z);
            rowb[4*j4+3] = (half_t)((rv[4*j4+3] - muK) * rsK * gm.w + bt.w);
        }
        #pragma unroll
        for (int j = 36; j < 48; ++j) rowb[j] = (half_t)0.f;
        #pragma unroll
        for (int i = 0; i < 6; ++i)
            *(half8_t*)(Kbuf + tid * 48 + 8 * i) = *(half8_t*)&rowb[8 * i];
    }
    // ---- Q: re-read own row, normalize (x 1/6) in place ----
    {
        float rv[36];
        const half_t* rp = Qbuf + tid * 48;
        #pragma unroll
        for (int j = 0; j < 36; ++j) rv[j] = (float)rp[j];
        half_t rowb[48];
        #pragma unroll
        for (int j4 = 0; j4 < 9; ++j4) {
            const float4 gm = *(const float4*)(qg + tid * 36 + 4 * j4);
            const float4 bt = *(const float4*)(qbeta + tid * 36 + 4 * j4);
            rowb[4*j4+0] = (half_t)(((rv[4*j4+0] - muQ) * rsQ * gm.x + bt.x) * (1.0f/6.0f));
            rowb[4*j4+1] = (half_t)(((rv[4*j4+1] - muQ) * rsQ * gm.y + bt.y) * (1.0f/6.0f));
            rowb[4*j4+2] = (half_t)(((rv[4*j4+2] - muQ) * rsQ * gm.z + bt.z) * (1.0f/6.0f));
            rowb[4*j4+3] = (half_t)(((rv[4*j4+3] - muQ) * rsQ * gm.w + bt.w) * (1.0f/6.0f));
        }
        #pragma unroll
        for (int j = 36; j < 48; ++j) rowb[j] = (half_t)0.f;
        #pragma unroll
        for (int i = 0; i < 6; ++i)
            *(half8_t*)(Qbuf + tid * 48 + 8 * i) = *(half8_t*)&rowb[8 * i];
    }
    __syncthreads();

    // ---- Q fragments (wave-local rows) ----
    half8_t Qf32[4];
    half4_t Qf16[4];
    #pragma unroll
    for (int nt = 0; nt < 4; ++nt) {
        const int row = 64 * w + 16 * nt + c;
        Qf32[nt] = *(const half8_t*)(Qbuf + row * 48 + 8 * g);
        Qf16[nt] = *(const half4_t*)(Qbuf + row * 48 + 32 + 4 * g);
    }

    // ---- kv-loop: 8 chunks x 32 keys, no barriers ----
    float m[4], lsum[4];
    f32x4 att[3][4];
    #pragma unroll
    for (int nt = 0; nt < 4; ++nt) {
        m[nt] = -1e30f; lsum[nt] = 0.f;
        #pragma unroll
        for (int mt2 = 0; mt2 < 3; ++mt2) att[mt2][nt] = (f32x4){0.f, 0.f, 0.f, 0.f};
    }

    #pragma unroll 1
    for (int ch = 0; ch < 8; ++ch) {
        half8_t Ka32[2];
        half4_t Ka16[2];
        #pragma unroll
        for (int mt = 0; mt < 2; ++mt) {
            const int row = 32 * ch + 16 * mt + c;
            Ka32[mt] = *(const half8_t*)(Kbuf + row * 48 + 8 * g);
            Ka16[mt] = *(const half4_t*)(Kbuf + row * 48 + 32 + 4 * g);
        }
        half4_t Va[3][2];
        #pragma unroll
        for (int mt2 = 0; mt2 < 3; ++mt2)
            #pragma unroll
            for (int kc = 0; kc < 2; ++kc)
                Va[mt2][kc] = *(const half4_t*)(Vt + (16 * mt2 + c) * 256 +
                                ((32 * ch + 16 * kc + 4 * g) ^ ((c & 7) << 2)));

        f32x4 S[2][4];
        #pragma unroll
        for (int mt = 0; mt < 2; ++mt)
            #pragma unroll
            for (int nt = 0; nt < 4; ++nt) {
                f32x4 z = {0.f, 0.f, 0.f, 0.f};
                z = __builtin_amdgcn_mfma_f32_16x16x32_f16(Ka32[mt], Qf32[nt], z, 0, 0, 0);
                z = __builtin_amdgcn_mfma_f32_16x16x16f16(Ka16[mt], Qf16[nt], z, 0, 0, 0);
                S[mt][nt] = z;
            }

        #pragma unroll
        for (int nt = 0; nt < 4; ++nt) {
            float cm = S[0][nt][0];
            cm = fmaxf(cm, S[0][nt][1]); cm = fmaxf(cm, S[0][nt][2]); cm = fmaxf(cm, S[0][nt][3]);
            cm = fmaxf(cm, S[1][nt][0]); cm = fmaxf(cm, S[1][nt][1]);
            cm = fmaxf(cm, S[1][nt][2]); cm = fmaxf(cm, S[1][nt][3]);
            cm = fmaxf(cm, __shfl_xor(cm, 16));
            cm = fmaxf(cm, __shfl_xor(cm, 32));
            const float newm  = fmaxf(m[nt], cm);
            const float alpha = __expf(m[nt] - newm);
            m[nt] = newm;
            lsum[nt] *= alpha;
            #pragma unroll
            for (int mt2 = 0; mt2 < 3; ++mt2) att[mt2][nt] *= alpha;

            half4_t P[2];
            #pragma unroll
            for (int mt = 0; mt < 2; ++mt) {
                const float p0 = __expf(S[mt][nt][0] - newm);
                const float p1 = __expf(S[mt][nt][1] - newm);
                const float p2 = __expf(S[mt][nt][2] - newm);
                const float p3 = __expf(S[mt][nt][3] - newm);
                lsum[nt] += (p0 + p1) + (p2 + p3);
                half4_t pp;
                pp[0] = (half_t)p0; pp[1] = (half_t)p1; pp[2] = (half_t)p2; pp[3] = (half_t)p3;
                P[mt] = pp;
            }
            #pragma unroll
            for (int mt2 = 0; mt2 < 3; ++mt2) {
                att[mt2][nt] = __builtin_amdgcn_mfma_f32_16x16x16f16(Va[mt2][0], P[0], att[mt2][nt], 0, 0, 0);
                att[mt2][nt] = __builtin_amdgcn_mfma_f32_16x16x16f16(Va[mt2][1], P[1], att[mt2][nt], 0, 0, 0);
            }
        }
    }

    // ---- finalize att -> Qbuf rows ----
    #pragma unroll
    for (int nt = 0; nt < 4; ++nt) {
        float lt = lsum[nt];
        lt += __shfl_xor(lt, 16);
        lt += __shfl_xor(lt, 32);
        const float inv = 1.0f / lt;
        const int row = 64 * w + 16 * nt + c;
        #pragma unroll
        for (int mt2 = 0; mt2 < 2; ++mt2)
            #pragma unroll
            for (int r = 0; r < 4; ++r)
                Qbuf[row * 48 + 16 * mt2 + 4 * g + r] = (half_t)(att[mt2][nt][r] * inv);
        if (g == 0) {
            #pragma unroll
            for (int r = 0; r < 4; ++r)
                Qbuf[row * 48 + 32 + r] = (half_t)(att[2][nt][r] * inv);
        }
    }
    __syncthreads();

    // ---- epilogue: l1+ReLU, joint LN, node-max (wave butterfly), head ----
    float at[36];
    #pragma unroll
    for (int j = 0; j < 36; ++j) at[j] = (float)Qbuf[tid * 48 + j];

    float a2[36];
    #pragma unroll
    for (int jj = 0; jj < 36; ++jj) {
        float s = l1b[jj];
        #pragma unroll
        for (int d = 0; d < 36; ++d) s += at[d] * l1W[jj * 36 + d];
        a2[jj] = fmaxf(s, 0.f);
    }

    float s1 = 0.f, s2 = 0.f;
    #pragma unroll
    for (int j = 0; j < 36; ++j) { s1 += a2[j]; s2 += a2[j] * a2[j]; }
    block_reduce2(s1, s2, red);
    const float mu  = s1 * (1.0f / 9216.0f);
    const float rs  = rsqrtf(s2 * (1.0f / 9216.0f) - mu * mu + LN_EPS);

    float a3[36];
    #pragma unroll
    for (int j = 0; j < 36; ++j) a3[j] = (a2[j] - mu) * rs;

    // wave-level max butterfly over 64 nodes
    #pragma unroll
    for (int off = 1; off < 64; off <<= 1)
        #pragma unroll
        for (int j = 0; j < 36; ++j)
            a3[j] = fmaxf(a3[j], __shfl_xor(a3[j], off));
    if (l == 0) {
        #pragma unroll
        for (int j = 0; j < 36; ++j) epi[w * 36 + j] = a3[j];
    }
    __syncthreads();
    if (tid < 36)
        epi[144 + tid] = fmaxf(fmaxf(epi[tid], epi[36 + tid]),
                               fmaxf(epi[72 + tid], epi[108 + tid]));
    __syncthreads();
    if (tid < 10) {
        float y = l2b[tid];
        #pragma unroll
        for (int j = 0; j < 36; ++j) y += epi[144 + j] * l2W[tid * 36 + j];
        epi[180 + tid] = y;
    }
    __syncthreads();
    if (tid == 0) {
        float mx = epi[180];
        #pragma unroll
        for (int cc = 1; cc < 10; ++cc) mx = fmaxf(mx, epi[180 + cc]);
        float se = 0.f;
        #pragma unroll
        for (int cc = 0; cc < 10; ++cc) se += __expf(epi[180 + cc] - mx);
        const float lse = mx + logf(se);
        #pragma unroll
        for (int cc = 0; cc < 10; ++cc) out[b * 10 + cc] = epi[180 + cc] - lse;
    }
}

// ===========================================================================
extern "C" void kernel_launch(void* const* d_in, const int* in_sizes, int n_in,
                              void* d_out, int out_size, void* d_ws, size_t ws_size,
                              hipStream_t stream)
{
    const float* x     = (const float*)d_in[0];
    const float* w1    = (const float*)d_in[1];
    const float* b1    = (const float*)d_in[2];
    const float* w2    = (const float*)d_in[3];
    const float* b2    = (const float*)d_in[4];
    const float* w3    = (const float*)d_in[5];
    const float* b3    = (const float*)d_in[6];
    const float* w4    = (const float*)d_in[7];
    const float* b4    = (const float*)d_in[8];
    const float* kW    = (const float*)d_in[9];
    const float* kb    = (const float*)d_in[10];
    const float* qW    = (const float*)d_in[11];
    const float* qb    = (const float*)d_in[12];
    const float* vW    = (const float*)d_in[13];
    const float* vb    = (const float*)d_in[14];
    const float* kg    = (const float*)d_in[15];
    const float* kbeta = (const float*)d_in[16];
    const float* qg    = (const float*)d_in[17];
    const float* qbeta = (const float*)d_in[18];
    const float* vg    = (const float*)d_in[19];
    const float* vbeta = (const float*)d_in[20];
    const float* l1W   = (const float*)d_in[21];
    const float* l1b   = (const float*)d_in[22];
    const float* l2W   = (const float*)d_in[23];
    const float* l2b   = (const float*)d_in[24];

    const int B = in_sizes[0] / (28 * 28);            // 2048
    half_t* hbuf = (half_t*)d_ws;                     // [B,256,32] fp16 = 33.5 MB
    half_t* F2 = (half_t*)((char*)d_ws + 33554432);
    half_t* F3 = F2 + 8192;
    half_t* F4 = F3 + 12288;

    prep_weights_kernel<<<dim3(64), dim3(256), 0, stream>>>(w2, w3, w4, F2, F3, F4);
    conv_fused_kernel<<<dim3(B), dim3(256), 0, stream>>>(
        x, w1, b1, b2, b3, b4, F2, F3, F4, hbuf);
    attn_head_kernel<<<dim3(B), dim3(256), 0, stream>>>(
        hbuf, kW, kb, qW, qb, vW, vb,
        kg, kbeta, qg, qbeta, vg, vbeta,
        l1W, l1b, l2W, l2b, (float*)d_out);
}

// Round 8
// 277.680 us; speedup vs baseline: 10.8007x; 1.0587x over previous
//
#include <hip/hip_runtime.h>
#include <math.h>

#define LN_EPS 1e-5f

typedef _Float16 half_t;
typedef _Float16 half8_t __attribute__((ext_vector_type(8)));
typedef _Float16 half4_t __attribute__((ext_vector_type(4)));
typedef _Float16 half2_t __attribute__((ext_vector_type(2)));
typedef float f32x4 __attribute__((ext_vector_type(4)));

// ===========================================================================
// Weight-prep: reorder conv weights into MFMA B-fragment order (fp16).
// ===========================================================================
__global__ void prep_weights_kernel(const float* __restrict__ w2,
                                    const float* __restrict__ w3,
                                    const float* __restrict__ w4,
                                    half_t* __restrict__ F2,
                                    half_t* __restrict__ F3,
                                    half_t* __restrict__ F4)
{
    const int bid = blockIdx.x;
    const int t   = threadIdx.x;
    const int flat0 = t * 2;
    const int l  = flat0 >> 3;
    const int j0 = flat0 & 7;

    int layer, sn;
    half_t* dst;
    if (bid < 16)      { layer = 2; sn = bid;      dst = F2; }
    else if (bid < 40) { layer = 3; sn = bid - 16; dst = F3; }
    else               { layer = 4; sn = bid - 40; dst = F4; }
    const int s  = sn >> 1;
    const int nt = sn & 1;
    const int oc = nt * 16 + (l & 15);

    float v[2];
    #pragma unroll
    for (int u = 0; u < 2; ++u) {
        const int j = j0 + u;
        const int k = s * 32 + ((l >> 4) * 8) + j;
        float val = 0.f;
        if (layer == 2) {
            const int ky = k >> 6, rem = k & 63, kx = rem >> 4, ic = rem & 15;
            if (oc < 20) val = w2[(oc * 16 + ic) * 16 + ky * 4 + kx];
        } else if (layer == 3) {
            const int ky = k / 96, rem = k % 96, kx = rem / 24, ic = rem % 24;
            if (oc < 24 && ic < 20) val = w3[(oc * 20 + ic) * 16 + ky * 4 + kx];
        } else {
            const int ky = k / 96, rem = k % 96, kx = rem / 24, ic = rem % 24;
            if (oc < 30) val = w4[(oc * 24 + ic) * 16 + ky * 4 + kx];
        }
        v[u] = val;
    }
    half2_t outv;
    outv[0] = (half_t)v[0];
    outv[1] = (half_t)v[1];
    *(half2_t*)&dst[(sn * 64 + l) * 8 + j0] = outv;
}

// ===========================================================================
// Fused conv stack, MFMA implicit GEMM.
// B-fragments loaded per-stage (no cross-stage register residency -> no spill).
// conv4 output staged in LDS, then coalesced float4 global writes.
// ===========================================================================
__global__ __launch_bounds__(256, 2) void conv_fused_kernel(
    const float* __restrict__ x,
    const float* __restrict__ w1, const float* __restrict__ b1,
    const float* __restrict__ b2, const float* __restrict__ b3,
    const float* __restrict__ b4,
    const half_t* __restrict__ F2, const half_t* __restrict__ F3,
    const half_t* __restrict__ F4,
    half_t* __restrict__ hout)
{
    __shared__ __attribute__((aligned(16))) char LBUF[45280];
    float*  xw = (float*)LBUF;
    char*   plane2b = LBUF;                 // conv2 out / conv4 stage region
    char*   plane1b = LBUF + 23232;         // conv1 out / conv3 out region
    half_t* plane2h = (half_t*)plane2b;
    half_t* plane1h = (half_t*)plane1b;
    half_t* plane3h = (half_t*)plane1b;
    half_t* stage   = (half_t*)plane2b;     // conv4 staging [256][32] fp16

    const int b    = blockIdx.x;
    const int tid  = threadIdx.x;
    const int wave = tid >> 6;
    const int l    = tid & 63;
    const int col  = l & 15;
    const int g    = l >> 4;

    {
        const float4* gx = (const float4*)(x + (size_t)b * 784);
        if (tid < 196) ((float4*)xw)[tid] = gx[tid];
        const int i = tid;
        if (i < 256) xw[784 + (i & 15) * 16 + (i >> 4)] = w1[i];
        if (tid < 16) xw[1040 + tid] = b1[tid];
    }
    __syncthreads();

    // ---- conv1 (fp32 VALU): 1->16, 28x28 -> 25x25, HWC fp16 out ----
    {
        const float* xs  = xw;
        const float* w1s = xw + 784;
        const float* b1s = xw + 1040;
        const int p0 = tid, p1 = tid + 256;
        const bool v2 = (tid + 512) < 625;
        const int p2 = v2 ? tid + 512 : 624;
        const int y0 = p0 / 25, x0 = p0 % 25;
        const int y1 = p1 / 25, x1 = p1 % 25;
        const int y2 = p2 / 25, x2 = p2 % 25;
        float a0[16], a1[16], a2[16];
        #pragma unroll
        for (int oc = 0; oc < 16; ++oc) { const float bb = b1s[oc]; a0[oc] = bb; a1[oc] = bb; a2[oc] = bb; }
        #pragma unroll
        for (int k = 0; k < 16; ++k) {
            const int ky = k >> 2, kx = k & 3;
            const float i0 = xs[(y0 + ky) * 28 + x0 + kx];
            const float i1 = xs[(y1 + ky) * 28 + x1 + kx];
            const float i2 = xs[(y2 + ky) * 28 + x2 + kx];
            #pragma unroll
            for (int oc4 = 0; oc4 < 4; ++oc4) {
                const float4 wv = *(const float4*)&w1s[k * 16 + oc4 * 4];
                const float wq[4] = {wv.x, wv.y, wv.z, wv.w};
                #pragma unroll
                for (int q = 0; q < 4; ++q) {
                    const int oc = oc4 * 4 + q;
                    a0[oc] += i0 * wq[q]; a1[oc] += i1 * wq[q]; a2[oc] += i2 * wq[q];
                }
            }
        }
        __syncthreads();   // xw reads done before plane1 writes overlap region? (disjoint, but cheap safety for x region reuse ordering)
        #pragma unroll
        for (int i2_ = 0; i2_ < 8; ++i2_) {
            half2_t h0, h1;
            h0[0] = (half_t)fmaxf(a0[2 * i2_], 0.f); h0[1] = (half_t)fmaxf(a0[2 * i2_ + 1], 0.f);
            h1[0] = (half_t)fmaxf(a1[2 * i2_], 0.f); h1[1] = (half_t)fmaxf(a1[2 * i2_ + 1], 0.f);
            *(half2_t*)&plane1h[p0 * 16 + 2 * i2_] = h0;
            *(half2_t*)&plane1h[p1 * 16 + 2 * i2_] = h1;
        }
        if (v2) {
            #pragma unroll
            for (int i2_ = 0; i2_ < 8; ++i2_) {
                half2_t h2v;
                h2v[0] = (half_t)fmaxf(a2[2 * i2_], 0.f); h2v[1] = (half_t)fmaxf(a2[2 * i2_ + 1], 0.f);
                *(half2_t*)&plane1h[p2 * 16 + 2 * i2_] = h2v;
            }
        }
    }
    __syncthreads();

    // ---- conv2 (MFMA): 16->20(pad24), 25x25 -> 22x22, K=256 (8 steps) ----
    {
        half8_t B2f[8][2];                       // loaded HERE (stage-local)
        const half8_t* Fv = (const half8_t*)F2;
        #pragma unroll
        for (int s = 0; s < 8; ++s) {
            B2f[s][0] = Fv[(s * 2 + 0) * 64 + l];
            B2f[s][1] = Fv[(s * 2 + 1) * 64 + l];
        }
        const float bias0 = b2[col];
        const float bias1 = (16 + col < 20) ? b2[16 + col] : 0.f;
        #pragma unroll 1
        for (int mt = wave; mt < 31; mt += 4) {
            const int pos = mt * 16 + col;
            const int py = pos / 22, px = pos - py * 22;
            const char* Ab = plane1b + (py * 25 + px) * 32 + g * 16;
            f32x4 c0 = {0.f, 0.f, 0.f, 0.f}, c1 = {0.f, 0.f, 0.f, 0.f};
            #pragma unroll
            for (int s = 0; s < 8; ++s) {
                const half8_t a = *(const half8_t*)(Ab + (s >> 1) * 800 + (s & 1) * 64);
                c0 = __builtin_amdgcn_mfma_f32_16x16x32_f16(a, B2f[s][0], c0, 0, 0, 0);
                c1 = __builtin_amdgcn_mfma_f32_16x16x32_f16(a, B2f[s][1], c1, 0, 0, 0);
            }
            #pragma unroll
            for (int r = 0; r < 4; ++r) {
                const int prow = mt * 16 + g * 4 + r;
                if (prow < 484) {
                    plane2h[prow * 24 + col] = (half_t)fmaxf(c0[r] + bias0, 0.f);
                    if (col < 8) {
                        const float v = (col < 4) ? fmaxf(c1[r] + bias1, 0.f) : 0.f;
                        plane2h[prow * 24 + 16 + col] = (half_t)v;
                    }
                }
            }
        }
    }
    __syncthreads();

    // ---- conv3 (MFMA): 24(in,pad)->24, 22x22 -> 19x19, K=384 (12 steps) ----
    {
        half8_t B3f[12][2];                      // loaded HERE
        const half8_t* Fv = (const half8_t*)F3;
        #pragma unroll
        for (int s = 0; s < 12; ++s) {
            B3f[s][0] = Fv[(s * 2 + 0) * 64 + l];
            B3f[s][1] = Fv[(s * 2 + 1) * 64 + l];
        }
        const float bias0 = b3[col];
        const float bias1 = b3[16 + (col & 7)];
        #pragma unroll 1
        for (int mt = wave; mt < 23; mt += 4) {
            const int pos = mt * 16 + col;
            const int py = pos / 19, px = pos - py * 19;
            const char* Ab = plane2b + (py * 22 + px) * 48 + g * 16;
            f32x4 c0 = {0.f, 0.f, 0.f, 0.f}, c1 = {0.f, 0.f, 0.f, 0.f};
            #pragma unroll
            for (int s = 0; s < 12; ++s) {
                const half8_t a = *(const half8_t*)(Ab + (s / 3) * 1056 + (s % 3) * 64);
                c0 = __builtin_amdgcn_mfma_f32_16x16x32_f16(a, B3f[s][0], c0, 0, 0, 0);
                c1 = __builtin_amdgcn_mfma_f32_16x16x32_f16(a, B3f[s][1], c1, 0, 0, 0);
            }
            #pragma unroll
            for (int r = 0; r < 4; ++r) {
                const int prow = mt * 16 + g * 4 + r;
                if (prow < 361) {
                    plane3h[prow * 24 + col] = (half_t)fmaxf(c0[r] + bias0, 0.f);
                    if (col < 8)
                        plane3h[prow * 24 + 16 + col] = (half_t)fmaxf(c1[r] + bias1, 0.f);
                }
            }
        }
    }
    __syncthreads();

    // ---- conv4 (MFMA): 24->30, 19x19 -> 16x16; stage in LDS ----
    {
        half8_t B4f[12][2];                      // loaded HERE
        const half8_t* Fv = (const half8_t*)F4;
        #pragma unroll
        for (int s = 0; s < 12; ++s) {
            B4f[s][0] = Fv[(s * 2 + 0) * 64 + l];
            B4f[s][1] = Fv[(s * 2 + 1) * 64 + l];
        }
        const float bias0 = b4[col];
        const float bias1 = (16 + col < 30) ? b4[16 + col] : 0.f;
        #pragma unroll 1
        for (int mt = wave; mt < 16; mt += 4) {
            const int pos = mt * 16 + col;
            const int py = pos >> 4, px = pos & 15;
            const char* Ab = plane1b + (py * 19 + px) * 48 + g * 16;   // plane3
            f32x4 c0 = {0.f, 0.f, 0.f, 0.f}, c1 = {0.f, 0.f, 0.f, 0.f};
            #pragma unroll
            for (int s = 0; s < 12; ++s) {
                const half8_t a = *(const half8_t*)(Ab + (s / 3) * 912 + (s % 3) * 64);
                c0 = __builtin_amdgcn_mfma_f32_16x16x32_f16(a, B4f[s][0], c0, 0, 0, 0);
                c1 = __builtin_amdgcn_mfma_f32_16x16x32_f16(a, B4f[s][1], c1, 0, 0, 0);
            }
            #pragma unroll
            for (int r = 0; r < 4; ++r) {
                const int prow = mt * 16 + g * 4 + r;   // < 256
                stage[prow * 32 + col] = (half_t)fmaxf(c0[r] + bias0, 0.f);
                if (col < 14)
                    stage[prow * 32 + 16 + col] = (half_t)fmaxf(c1[r] + bias1, 0.f);
            }
        }
        // coord channels (half2 per thread)
        half2_t cc;
        cc[0] = (half_t)((float)(tid & 15) * 0.0625f);
        cc[1] = (half_t)((float)(tid >> 4) * 0.0625f);
        *(half2_t*)&stage[tid * 32 + 30] = cc;
    }
    __syncthreads();

    // ---- coalesced copy LDS stage -> hbuf (full 64B lines) ----
    {
        const float4* sst  = (const float4*)stage;
        float4* gdst = (float4*)(hout + (size_t)b * 8192);
        #pragma unroll
        for (int k2 = 0; k2 < 4; ++k2)
            gdst[tid + 256 * k2] = sst[tid + 256 * k2];
    }
}

// ===========================================================================
__device__ __forceinline__ void block_reduce2(float& s1, float& s2, float* red)
{
    #pragma unroll
    for (int off = 32; off > 0; off >>= 1) {
        s1 += __shfl_down(s1, off);
        s2 += __shfl_down(s2, off);
    }
    const int lane = threadIdx.x & 63;
    const int wid  = threadIdx.x >> 6;
    if (lane == 0) { red[wid * 2] = s1; red[wid * 2 + 1] = s2; }
    __syncthreads();
    s1 = red[0] + red[2] + red[4] + red[6];
    s2 = red[1] + red[3] + red[5] + red[7];
    __syncthreads();
}

// ===========================================================================
// Attention + head, full-MFMA version.
// LDS regions:
//   Qbuf [256][48] fp16 (24576B) : proj scratch -> Q rows -> att rows
//   Kbuf [256][48] fp16 (24576B) : K rows            (96B rows: frag reads conflict-free)
//   Vt   [48][256]  fp16 (24576B) : V^T, XOR-swizzled (halfidx ^ ((feat&7)<<2))
//   mbuf [256][36]  f32  (over Kbuf+Vt, epilogue max-reduction)
// ===========================================================================
__global__ __launch_bounds__(256, 2) void attn_head_kernel(
    const half_t* __restrict__ hbuf,
    const float* __restrict__ kW, const float* __restrict__ kb,
    const float* __restrict__ qW, const float* __restrict__ qb,
    const float* __restrict__ vW, const float* __restrict__ vb,
    const float* __restrict__ kg, const float* __restrict__ kbeta,
    const float* __restrict__ qg, const float* __restrict__ qbeta,
    const float* __restrict__ vg, const float* __restrict__ vbeta,
    const float* __restrict__ l1W, const float* __restrict__ l1b,
    const float* __restrict__ l2W, const float* __restrict__ l2b,
    float* __restrict__ out)
{
    __shared__ __attribute__((aligned(16))) char LDS[73728];
    __shared__ float red[8];
    __shared__ float epi[196];     // 4*36 wave-max + 36 final + 10 y + lse

    half_t* Qbuf = (half_t*)LDS;
    half_t* Kbuf = (half_t*)(LDS + 24576);
    half_t* Vt   = (half_t*)(LDS + 49152);
    float*  mbuf = (float*)(LDS + 24576);

    const int b   = blockIdx.x;
    const int tid = threadIdx.x;
    const int w   = tid >> 6;
    const int l   = tid & 63;
    const int c   = l & 15;
    const int g   = l >> 4;

    // ---- h A-fragments (wave w owns node rows 64w..64w+63) ----
    half8_t hA[4];
    #pragma unroll
    for (int mt = 0; mt < 4; ++mt)
        hA[mt] = *(const half8_t*)(hbuf + ((size_t)b * 256 + 64 * w + 16 * mt + c) * 32 + 8 * g);

    // ---- three projections: K (0), V (1), Q (2) ----
    #pragma unroll 1
    for (int pj = 0; pj < 3; ++pj) {
        const float* W    = (pj == 0) ? kW : (pj == 1) ? vW : qW;
        const float* bias = (pj == 0) ? kb : (pj == 1) ? vb : qb;
        const float* gam  = (pj == 0) ? kg : (pj == 1) ? vg : qg;
        const float* bet  = (pj == 0) ? kbeta : (pj == 1) ? vbeta : qbeta;

        // B-fragments from W [36][32] f32 (rows >=36 zero-padded)
        half8_t Bf[3];
        #pragma unroll
        for (int nt = 0; nt < 3; ++nt) {
            const int row = 16 * nt + c;
            half8_t hb;
            if (row < 36) {
                const float4 w0 = *(const float4*)(W + row * 32 + 8 * g);
                const float4 w1 = *(const float4*)(W + row * 32 + 8 * g + 4);
                hb[0] = (half_t)w0.x; hb[1] = (half_t)w0.y; hb[2] = (half_t)w0.z; hb[3] = (half_t)w0.w;
                hb[4] = (half_t)w1.x; hb[5] = (half_t)w1.y; hb[6] = (half_t)w1.z; hb[7] = (half_t)w1.w;
            } else {
                #pragma unroll
                for (int j = 0; j < 8; ++j) hb[j] = (half_t)0.f;
            }
            Bf[nt] = hb;
        }
        // C init = bias (same for all rows of a column)
        f32x4 acc[4][3];
        #pragma unroll
        for (int nt = 0; nt < 3; ++nt) {
            const int o = 16 * nt + c;
            const float bv = (o < 36) ? bias[o] : 0.f;
            #pragma unroll
            for (int mt = 0; mt < 4; ++mt) acc[mt][nt] = (f32x4){bv, bv, bv, bv};
        }
        #pragma unroll
        for (int mt = 0; mt < 4; ++mt)
            #pragma unroll
            for (int nt = 0; nt < 3; ++nt)
                acc[mt][nt] = __builtin_amdgcn_mfma_f32_16x16x32_f16(hA[mt], Bf[nt], acc[mt][nt], 0, 0, 0);

        // scatter C -> scratch [node][feat48]
        #pragma unroll
        for (int mt = 0; mt < 4; ++mt)
            #pragma unroll
            for (int nt = 0; nt < 3; ++nt)
                #pragma unroll
                for (int r = 0; r < 4; ++r)
                    Qbuf[(64 * w + 16 * mt + 4 * g + r) * 48 + 16 * nt + c] = (half_t)acc[mt][nt][r];
        __syncthreads();

        // per-node joint LayerNorm (thread = node)
        float rv[36];
        {
            const half_t* rp = Qbuf + tid * 48;
            #pragma unroll
            for (int j = 0; j < 36; ++j) rv[j] = (float)rp[j];
        }
        float s1 = 0.f, s2 = 0.f;
        #pragma unroll
        for (int j = 0; j < 36; ++j) { s1 += rv[j]; s2 += rv[j] * rv[j]; }
        block_reduce2(s1, s2, red);
        const float mu  = s1 * (1.0f / 9216.0f);
        const float var = s2 * (1.0f / 9216.0f) - mu * mu;
        const float rs  = rsqrtf(var + LN_EPS);

        half_t rowb[48];
        #pragma unroll
        for (int j4 = 0; j4 < 9; ++j4) {
            const float4 gm = *(const float4*)(gam + tid * 36 + 4 * j4);
            const float4 bt = *(const float4*)(bet + tid * 36 + 4 * j4);
            float f0 = (rv[4*j4+0] - mu) * rs * gm.x + bt.x;
            float f1 = (rv[4*j4+1] - mu) * rs * gm.y + bt.y;
            float f2 = (rv[4*j4+2] - mu) * rs * gm.z + bt.z;
            float f3 = (rv[4*j4+3] - mu) * rs * gm.w + bt.w;
            if (pj == 2) { f0 *= (1.0f/6.0f); f1 *= (1.0f/6.0f); f2 *= (1.0f/6.0f); f3 *= (1.0f/6.0f); }
            rowb[4*j4+0] = (half_t)f0; rowb[4*j4+1] = (half_t)f1;
            rowb[4*j4+2] = (half_t)f2; rowb[4*j4+3] = (half_t)f3;
        }
        #pragma unroll
        for (int j = 36; j < 48; ++j) rowb[j] = (half_t)0.f;

        if (pj == 0) {
            #pragma unroll
            for (int i = 0; i < 6; ++i)
                *(half8_t*)(Kbuf + tid * 48 + 8 * i) = *(half8_t*)&rowb[8 * i];
        } else if (pj == 1) {
            #pragma unroll
            for (int j = 0; j < 36; ++j)
                Vt[j * 256 + (tid ^ ((j & 7) << 2))] = rowb[j];
        } else {
            #pragma unroll
            for (int i = 0; i < 6; ++i)
                *(half8_t*)(Qbuf + tid * 48 + 8 * i) = *(half8_t*)&rowb[8 * i];
        }
        __syncthreads();
    }

    // ---- Q fragments (wave-local rows), held in registers ----
    half8_t Qf32[4];
    half4_t Qf16[4];
    #pragma unroll
    for (int nt = 0; nt < 4; ++nt) {
        const int row = 64 * w + 16 * nt + c;
        Qf32[nt] = *(const half8_t*)(Qbuf + row * 48 + 8 * g);
        Qf16[nt] = *(const half4_t*)(Qbuf + row * 48 + 32 + 4 * g);
    }

    // ---- kv-loop: 8 chunks x 32 keys, no barriers ----
    float m[4], lsum[4];
    f32x4 att[3][4];
    #pragma unroll
    for (int nt = 0; nt < 4; ++nt) {
        m[nt] = -1e30f; lsum[nt] = 0.f;
        #pragma unroll
        for (int mt2 = 0; mt2 < 3; ++mt2) att[mt2][nt] = (f32x4){0.f, 0.f, 0.f, 0.f};
    }

    #pragma unroll 1
    for (int ch = 0; ch < 8; ++ch) {
        half8_t Ka32[2];
        half4_t Ka16[2];
        #pragma unroll
        for (int mt = 0; mt < 2; ++mt) {
            const int row = 32 * ch + 16 * mt + c;
            Ka32[mt] = *(const half8_t*)(Kbuf + row * 48 + 8 * g);
            Ka16[mt] = *(const half4_t*)(Kbuf + row * 48 + 32 + 4 * g);
        }
        half4_t Va[3][2];
        #pragma unroll
        for (int mt2 = 0; mt2 < 3; ++mt2)
            #pragma unroll
            for (int kc = 0; kc < 2; ++kc)
                Va[mt2][kc] = *(const half4_t*)(Vt + (16 * mt2 + c) * 256 +
                                ((32 * ch + 16 * kc + 4 * g) ^ ((c & 7) << 2)));

        // S^T chunk: rows = keys, cols = qrows
        f32x4 S[2][4];
        #pragma unroll
        for (int mt = 0; mt < 2; ++mt)
            #pragma unroll
            for (int nt = 0; nt < 4; ++nt) {
                f32x4 z = {0.f, 0.f, 0.f, 0.f};
                z = __builtin_amdgcn_mfma_f32_16x16x32_f16(Ka32[mt], Qf32[nt], z, 0, 0, 0);
                z = __builtin_amdgcn_mfma_f32_16x16x16f16(Ka16[mt], Qf16[nt], z, 0, 0, 0);
                S[mt][nt] = z;
            }

        // online softmax + PV per qrow-tile
        #pragma unroll
        for (int nt = 0; nt < 4; ++nt) {
            float cm = S[0][nt][0];
            cm = fmaxf(cm, S[0][nt][1]); cm = fmaxf(cm, S[0][nt][2]); cm = fmaxf(cm, S[0][nt][3]);
            cm = fmaxf(cm, S[1][nt][0]); cm = fmaxf(cm, S[1][nt][1]);
            cm = fmaxf(cm, S[1][nt][2]); cm = fmaxf(cm, S[1][nt][3]);
            cm = fmaxf(cm, __shfl_xor(cm, 16));
            cm = fmaxf(cm, __shfl_xor(cm, 32));
            const float newm  = fmaxf(m[nt], cm);
            const float alpha = __expf(m[nt] - newm);
            m[nt] = newm;
            lsum[nt] *= alpha;
            #pragma unroll
            for (int mt2 = 0; mt2 < 3; ++mt2) att[mt2][nt] *= alpha;

            half4_t P[2];
            #pragma unroll
            for (int mt = 0; mt < 2; ++mt) {
                const float p0 = __expf(S[mt][nt][0] - newm);
                const float p1 = __expf(S[mt][nt][1] - newm);
                const float p2 = __expf(S[mt][nt][2] - newm);
                const float p3 = __expf(S[mt][nt][3] - newm);
                lsum[nt] += (p0 + p1) + (p2 + p3);
                half4_t pp;
                pp[0] = (half_t)p0; pp[1] = (half_t)p1; pp[2] = (half_t)p2; pp[3] = (half_t)p3;
                P[mt] = pp;
            }
            #pragma unroll
            for (int mt2 = 0; mt2 < 3; ++mt2) {
                att[mt2][nt] = __builtin_amdgcn_mfma_f32_16x16x16f16(Va[mt2][0], P[0], att[mt2][nt], 0, 0, 0);
                att[mt2][nt] = __builtin_amdgcn_mfma_f32_16x16x16f16(Va[mt2][1], P[1], att[mt2][nt], 0, 0, 0);
            }
        }
    }

    // ---- finalize att -> Qbuf rows ----
    #pragma unroll
    for (int nt = 0; nt < 4; ++nt) {
        float lt = lsum[nt];
        lt += __shfl_xor(lt, 16);
        lt += __shfl_xor(lt, 32);
        const float inv = 1.0f / lt;
        const int row = 64 * w + 16 * nt + c;
        #pragma unroll
        for (int mt2 = 0; mt2 < 2; ++mt2)
            #pragma unroll
            for (int r = 0; r < 4; ++r)
                Qbuf[row * 48 + 16 * mt2 + 4 * g + r] = (half_t)(att[mt2][nt][r] * inv);
        if (g == 0) {
            #pragma unroll
            for (int r = 0; r < 4; ++r)
                Qbuf[row * 48 + 32 + r] = (half_t)(att[2][nt][r] * inv);
        }
    }
    __syncthreads();

    // ---- epilogue: l1+ReLU, joint LN, node-max (wave butterfly), head ----
    float at[36];
    #pragma unroll
    for (int j = 0; j < 36; ++j) at[j] = (float)Qbuf[tid * 48 + j];

    float a2[36];
    #pragma unroll
    for (int jj = 0; jj < 36; ++jj) {
        float s = l1b[jj];
        #pragma unroll
        for (int d = 0; d < 36; ++d) s += at[d] * l1W[jj * 36 + d];
        a2[jj] = fmaxf(s, 0.f);
    }

    float s1 = 0.f, s2 = 0.f;
    #pragma unroll
    for (int j = 0; j < 36; ++j) { s1 += a2[j]; s2 += a2[j] * a2[j]; }
    block_reduce2(s1, s2, red);
    const float mu  = s1 * (1.0f / 9216.0f);
    const float rs  = rsqrtf(s2 * (1.0f / 9216.0f) - mu * mu + LN_EPS);

    float a3[36];
    #pragma unroll
    for (int j = 0; j < 36; ++j) a3[j] = (a2[j] - mu) * rs;

    // wave-level max butterfly over 64 nodes
    #pragma unroll
    for (int off = 1; off < 64; off <<= 1)
        #pragma unroll
        for (int j = 0; j < 36; ++j)
            a3[j] = fmaxf(a3[j], __shfl_xor(a3[j], off));
    if (l == 0) {
        #pragma unroll
        for (int j = 0; j < 36; ++j) epi[w * 36 + j] = a3[j];
    }
    __syncthreads();
    if (tid < 36)
        epi[144 + tid] = fmaxf(fmaxf(epi[tid], epi[36 + tid]),
                               fmaxf(epi[72 + tid], epi[108 + tid]));
    __syncthreads();
    if (tid < 10) {
        float y = l2b[tid];
        #pragma unroll
        for (int j = 0; j < 36; ++j) y += epi[144 + j] * l2W[tid * 36 + j];
        epi[180 + tid] = y;
    }
    __syncthreads();
    if (tid == 0) {
        float mx = epi[180];
        #pragma unroll
        for (int cc = 1; cc < 10; ++cc) mx = fmaxf(mx, epi[180 + cc]);
        float se = 0.f;
        #pragma unroll
        for (int cc = 0; cc < 10; ++cc) se += __expf(epi[180 + cc] - mx);
        const float lse = mx + logf(se);
        #pragma unroll
        for (int cc = 0; cc < 10; ++cc) out[b * 10 + cc] = epi[180 + cc] - lse;
    }
}

// ===========================================================================
extern "C" void kernel_launch(void* const* d_in, const int* in_sizes, int n_in,
                              void* d_out, int out_size, void* d_ws, size_t ws_size,
                              hipStream_t stream)
{
    const float* x     = (const float*)d_in[0];
    const float* w1    = (const float*)d_in[1];
    const float* b1    = (const float*)d_in[2];
    const float* w2    = (const float*)d_in[3];
    const float* b2    = (const float*)d_in[4];
    const float* w3    = (const float*)d_in[5];
    const float* b3    = (const float*)d_in[6];
    const float* w4    = (const float*)d_in[7];
    const float* b4    = (const float*)d_in[8];
    const float* kW    = (const float*)d_in[9];
    const float* kb    = (const float*)d_in[10];
    const float* qW    = (const float*)d_in[11];
    const float* qb    = (const float*)d_in[12];
    const float* vW    = (const float*)d_in[13];
    const float* vb    = (const float*)d_in[14];
    const float* kg    = (const float*)d_in[15];
    const float* kbeta = (const float*)d_in[16];
    const float* qg    = (const float*)d_in[17];
    const float* qbeta = (const float*)d_in[18];
    const float* vg    = (const float*)d_in[19];
    const float* vbeta = (const float*)d_in[20];
    const float* l1W   = (const float*)d_in[21];
    const float* l1b   = (const float*)d_in[22];
    const float* l2W   = (const float*)d_in[23];
    const float* l2b   = (const float*)d_in[24];

    const int B = in_sizes[0] / (28 * 28);            // 2048
    half_t* hbuf = (half_t*)d_ws;                     // [B,256,32] fp16 = 33.5 MB
    half_t* F2 = (half_t*)((char*)d_ws + 33554432);
    half_t* F3 = F2 + 8192;
    half_t* F4 = F3 + 12288;

    prep_weights_kernel<<<dim3(64), dim3(256), 0, stream>>>(w2, w3, w4, F2, F3, F4);
    conv_fused_kernel<<<dim3(B), dim3(256), 0, stream>>>(
        x, w1, b1, b2, b3, b4, F2, F3, F4, hbuf);
    attn_head_kernel<<<dim3(B), dim3(256), 0, stream>>>(
        hbuf, kW, kb, qW, qb, vW, vb,
        kg, kbeta, qg, qbeta, vg, vbeta,
        l1W, l1b, l2W, l2b, (float*)d_out);
}